// Round 4
// baseline (1319.737 us; speedup 1.0000x reference)
//
#include <hip/hip_runtime.h>
#include <math.h>

// Problem dims (fixed)
#define B_ 4
#define T_ 1024
#define C_ 256
#define D_ 256
#define H_ 512
#define NH_ 8
#define HD_ 64
#define INTER_ 2048
#define L_ 4
#define CB_ 128   // context_backward; context_forward = 0

typedef short bf16x8 __attribute__((ext_vector_type(8)));
typedef float f32x4 __attribute__((ext_vector_type(4)));

__device__ __forceinline__ float gelu_exact(float x) {
    return 0.5f * x * (1.0f + erff(x * 0.70710678118654752f));
}

// fp32 -> bf16 round-to-nearest-even
__device__ __forceinline__ unsigned short f2bf(float f) {
    unsigned u = __float_as_uint(f);
    u += 0x7fffu + ((u >> 16) & 1u);
    return (unsigned short)(u >> 16);
}

// ---------------------------------------------------------------------------
// bf16 MFMA GEMM: out[M,N] = epi(A[M,K](bf16) @ BT[N,K](bf16)^T + bias)
// 128x128 tile, 256 threads (4 waves 2x2), each wave 4x4 of 16x16x32 MFMA.
// BK=32, global_load_lds width-16 staging.
// SPLIT=1: QKV mode. N=1536 (q 0-511, k 512-1023, v 1024-1535). Epilogue
// applies bias + RoPE (rotate pairs d/d+32, q scaled 0.125) and writes bf16
// q,k [M,512]; v written transposed to vT[b][h][64][T] bf16.
// ---------------------------------------------------------------------------
template<int ACT, int RES, int OBF, int SPLIT>
__global__ __launch_bounds__(256) void mm_k(
    const unsigned short* __restrict__ A, const unsigned short* __restrict__ BT,
    const float* __restrict__ b0, const float* __restrict__ b1,
    const float* __restrict__ b2,
    const float* res, const int* __restrict__ ts,
    void* o0, void* o1, void* o2,
    const int M, const int N, const int K)
{
    __shared__ unsigned short As[128 * 32];
    __shared__ unsigned short Bs[128 * 32];

    const int tid  = threadIdx.x;
    const int lane = tid & 63;
    const int w    = tid >> 6;
    const int m0   = blockIdx.y * 128;
    const int n0   = blockIdx.x * 128;
    const int wm   = (w >> 1) * 64;
    const int wn   = (w & 1) * 64;
    const int l16  = lane & 15;
    const int g16  = lane >> 4;
    const int fk   = g16 * 8;

    f32x4 acc[4][4] = {};

    const int c0 = (w << 6) + lane;
    const int c1 = c0 + 256;

    const unsigned short* Abase = A  + (size_t)m0 * K;
    const unsigned short* Bbase = BT + (size_t)n0 * K;

    for (int k0 = 0; k0 < K; k0 += 32) {
        __syncthreads();
        const unsigned short* ga0 = Abase + (size_t)(c0 >> 2) * K + k0 + (c0 & 3) * 8;
        const unsigned short* ga1 = Abase + (size_t)(c1 >> 2) * K + k0 + (c1 & 3) * 8;
        __builtin_amdgcn_global_load_lds(
            (const __attribute__((address_space(1))) unsigned*)ga0,
            (__attribute__((address_space(3))) unsigned*)(As + (size_t)(w << 6) * 8), 16, 0, 0);
        __builtin_amdgcn_global_load_lds(
            (const __attribute__((address_space(1))) unsigned*)ga1,
            (__attribute__((address_space(3))) unsigned*)(As + (size_t)(256 + (w << 6)) * 8), 16, 0, 0);
        const unsigned short* gb0 = Bbase + (size_t)(c0 >> 2) * K + k0 + (c0 & 3) * 8;
        const unsigned short* gb1 = Bbase + (size_t)(c1 >> 2) * K + k0 + (c1 & 3) * 8;
        __builtin_amdgcn_global_load_lds(
            (const __attribute__((address_space(1))) unsigned*)gb0,
            (__attribute__((address_space(3))) unsigned*)(Bs + (size_t)(w << 6) * 8), 16, 0, 0);
        __builtin_amdgcn_global_load_lds(
            (const __attribute__((address_space(1))) unsigned*)gb1,
            (__attribute__((address_space(3))) unsigned*)(Bs + (size_t)(256 + (w << 6)) * 8), 16, 0, 0);
        __syncthreads();

        bf16x8 a[4], b[4];
#pragma unroll
        for (int t = 0; t < 4; ++t)
            a[t] = *(const bf16x8*)&As[(wm + t * 16 + l16) * 32 + fk];
#pragma unroll
        for (int t = 0; t < 4; ++t)
            b[t] = *(const bf16x8*)&Bs[(wn + t * 16 + l16) * 32 + fk];
#pragma unroll
        for (int i = 0; i < 4; ++i)
#pragma unroll
            for (int j = 0; j < 4; ++j)
                acc[i][j] = __builtin_amdgcn_mfma_f32_16x16x32_bf16(a[i], b[j], acc[i][j], 0, 0, 0);
    }

    if (SPLIT) {
        // wave's 64-col strip = one head of one of q/k/v
        const int gnb   = n0 + wn;
        const int which = gnb >> 9;
        if (which < 2) {
            unsigned short* oo = which ? (unsigned short*)o1 : (unsigned short*)o0;
            const float* bb = which ? b1 : b0;
            const int lnb = gnb & 511;
#pragma unroll
            for (int i = 0; i < 4; ++i) {
                const int gmb = m0 + wm + i * 16 + g16 * 4;
#pragma unroll
                for (int j = 0; j < 2; ++j) {
                    const int d = j * 16 + l16;              // 0..31
                    const float freq = __expf(-0.2878231366242558f * (float)d);
                    const float bv1 = bb[lnb + j * 16 + l16];
                    const float bv2 = bb[lnb + j * 16 + 32 + l16];
#pragma unroll
                    for (int r = 0; r < 4; ++r) {
                        const int row = gmb + r;
                        const float ang = (float)ts[row] * freq;
                        const float cc = cosf(ang);
                        const float ss = sinf(ang);
                        float v1 = acc[i][j][r] + bv1;
                        float v2 = acc[i][j + 2][r] + bv2;
                        float r1 = v1 * cc - v2 * ss;
                        float r2 = v2 * cc + v1 * ss;
                        if (which == 0) { r1 *= 0.125f; r2 *= 0.125f; }
                        oo[(size_t)row * 512 + lnb + j * 16 + l16]      = f2bf(r1);
                        oo[(size_t)row * 512 + lnb + j * 16 + 32 + l16] = f2bf(r2);
                    }
                }
            }
        } else {
            // v: write transposed vT[(b*8+hv)*64 + n][t]
            const int hv = (gnb - 1024) >> 6;
            unsigned short* oo = (unsigned short*)o2;
#pragma unroll
            for (int i = 0; i < 4; ++i) {
                const int gmb = m0 + wm + i * 16 + g16 * 4;   // 4 consecutive rows
                const int bb_ = gmb >> 10;
                const int t0  = gmb & 1023;
#pragma unroll
                for (int j = 0; j < 4; ++j) {
                    const int n = j * 16 + l16;
                    const float bv = b2[(gnb & 511) + j * 16 + l16];
                    ushort4 ov;
                    ov.x = f2bf(acc[i][j][0] + bv);
                    ov.y = f2bf(acc[i][j][1] + bv);
                    ov.z = f2bf(acc[i][j][2] + bv);
                    ov.w = f2bf(acc[i][j][3] + bv);
                    *(ushort4*)&oo[((size_t)(bb_ * 8 + hv) * 64 + n) * 1024 + t0] = ov;
                }
            }
        }
        return;
    }

    // generic epilogue: C/D layout col=lane&15, row=(lane>>4)*4+reg
#pragma unroll
    for (int i = 0; i < 4; ++i) {
        const int gmb = m0 + wm + i * 16 + g16 * 4;
#pragma unroll
        for (int j = 0; j < 4; ++j) {
            const int gn = n0 + wn + j * 16 + l16;
            const float bv = b0[gn];
#pragma unroll
            for (int r = 0; r < 4; ++r) {
                float cv = acc[i][j][r] + bv;
                if (ACT) cv = gelu_exact(cv);
                if (RES) cv += res[(size_t)(gmb + r) * 512 + gn];
                if (OBF) ((unsigned short*)o0)[(size_t)(gmb + r) * N + gn] = f2bf(cv);
                else     ((float*)o0)[(size_t)(gmb + r) * N + gn] = cv;
            }
        }
    }
}

// ---------------------------------------------------------------------------
// Transpose + fp32->bf16: src [R,Cc] fp32 -> dst [Cc,R] bf16. 64x64 tiles.
// ---------------------------------------------------------------------------
__global__ __launch_bounds__(256) void tconv_k(
    const float* __restrict__ src, unsigned short* __restrict__ dst,
    int R, int Cc, long slay, long dlay)
{
    __shared__ float tile[64][65];
    const int t = threadIdx.x;
    src += (size_t)blockIdx.z * slay;
    dst += (size_t)blockIdx.z * dlay;
    const int r0 = blockIdx.y * 64, c0 = blockIdx.x * 64;
    const int tr = t >> 4, tc = (t & 15) * 4;
#pragma unroll
    for (int i = 0; i < 4; ++i) {
        float4 v = *(const float4*)&src[(size_t)(r0 + tr + i * 16) * Cc + c0 + tc];
        tile[tr + i * 16][tc + 0] = v.x;
        tile[tr + i * 16][tc + 1] = v.y;
        tile[tr + i * 16][tc + 2] = v.z;
        tile[tr + i * 16][tc + 3] = v.w;
    }
    __syncthreads();
#pragma unroll
    for (int i = 0; i < 4; ++i) {
        const int n = tr + i * 16;
        ushort4 o;
        o.x = f2bf(tile[tc + 0][n]);
        o.y = f2bf(tile[tc + 1][n]);
        o.z = f2bf(tile[tc + 2][n]);
        o.w = f2bf(tile[tc + 3][n]);
        *(ushort4*)&dst[(size_t)(c0 + n) * R + r0 + tc] = o;
    }
}

// elementwise fp32 -> bf16
__global__ __launch_bounds__(256) void conv_k(
    const float* __restrict__ src, unsigned short* __restrict__ dst)
{
    const int i = (blockIdx.x * 256 + threadIdx.x) * 4;
    float4 v = *(const float4*)&src[i];
    ushort4 o = {f2bf(v.x), f2bf(v.y), f2bf(v.z), f2bf(v.w)};
    *(ushort4*)&dst[i] = o;
}

// ---------------------------------------------------------------------------
// LayerNorm over H=512, bf16 output.
// ---------------------------------------------------------------------------
__global__ __launch_bounds__(256) void ln_k(
    const float* __restrict__ x, const float* __restrict__ g,
    const float* __restrict__ b, unsigned short* __restrict__ out)
{
    const int row = blockIdx.x;
    const int tid = threadIdx.x;
    const float* xr = x + (size_t)row * H_;

    float v0 = xr[tid];
    float v1 = xr[tid + 256];

    float s = v0 + v1;
#pragma unroll
    for (int off = 32; off; off >>= 1) s += __shfl_xor(s, off);

    __shared__ float red[4];
    const int wave = tid >> 6;
    if ((tid & 63) == 0) red[wave] = s;
    __syncthreads();
    const float mean = (red[0] + red[1] + red[2] + red[3]) * (1.0f / (float)H_);

    const float d0 = v0 - mean, d1 = v1 - mean;
    float q = d0 * d0 + d1 * d1;
#pragma unroll
    for (int off = 32; off; off >>= 1) q += __shfl_xor(q, off);
    __syncthreads();
    if ((tid & 63) == 0) red[wave] = q;
    __syncthreads();
    const float var = (red[0] + red[1] + red[2] + red[3]) * (1.0f / (float)H_);
    const float rstd = rsqrtf(var + 1e-5f);

    out[(size_t)row * H_ + tid]       = f2bf(d0 * rstd * g[tid] + b[tid]);
    out[(size_t)row * H_ + tid + 256] = f2bf(d1 * rstd * g[tid + 256] + b[tid + 256]);
}

// ---------------------------------------------------------------------------
// MFMA banded attention. One block per (b, h, 64-query tile); 4 waves.
// Inputs: q,k bf16 [B*T,512] (rotated; q pre-scaled), vT bf16 [b][h][64][T].
// Window rows klo..klo+191 (always in-range); band mask applied in-register.
// S via mfma (wave w owns q-rows 16w..16w+15); softmax in regs; P -> LDS
// bf16 (A-frag layout); PV via mfma; o bf16 [B*T,512].
// ---------------------------------------------------------------------------
#define AWIN 192
#define AKS 72    // ushort stride Qs/Ks (144B: 16B-aligned, 2-way banks)
#define AVS 200   // ushort stride Vt/Pb (400B: 16B-aligned, 2-way banks)

__global__ __launch_bounds__(256) void attn_k(
    const unsigned short* __restrict__ q, const unsigned short* __restrict__ k,
    const unsigned short* __restrict__ vT, const int* __restrict__ smask,
    unsigned short* __restrict__ o)
{
    __shared__ unsigned short Qs[64 * AKS];
    __shared__ unsigned short Ks[AWIN * AKS];
    __shared__ unsigned short Vt[64 * AVS];
    __shared__ unsigned short Pb[64 * AVS];

    const int blk = blockIdx.x;
    const int qt = blk & 15;
    const int h  = (blk >> 4) & 7;
    const int b  = blk >> 7;
    const int tid  = threadIdx.x;
    const int lane = tid & 63;
    const int w    = tid >> 6;
    const int l16  = lane & 15;
    const int g16  = lane >> 4;

    const int qlo = qt * 64;
    const int klo = (qlo >= CB_) ? (qlo - CB_) : 0;

    // ---- stage ----
    {
        const unsigned short* gq = q + ((size_t)(b * 1024 + qlo)) * 512 + h * 64;
        for (int c = tid; c < 64 * 16; c += 256) {
            const int row = c >> 4, c4 = (c & 15) * 4;
            *(ushort4*)&Qs[row * AKS + c4] = *(const ushort4*)&gq[(size_t)row * 512 + c4];
        }
        const unsigned short* gk = k + ((size_t)(b * 1024 + klo)) * 512 + h * 64;
        for (int c = tid; c < AWIN * 16; c += 256) {
            const int row = c >> 4, c4 = (c & 15) * 4;
            *(ushort4*)&Ks[row * AKS + c4] = *(const ushort4*)&gk[(size_t)row * 512 + c4];
        }
        const unsigned short* gv = vT + ((size_t)(b * 8 + h) * 64) * 1024 + klo;
        for (int c = tid; c < 64 * 48; c += 256) {
            const int n = c / 48, kc = (c - n * 48) * 4;
            *(ushort4*)&Vt[n * AVS + kc] = *(const ushort4*)&gv[(size_t)n * 1024 + kc];
        }
    }
    __syncthreads();

    // ---- S = Q @ K^T (wave w: q-rows 16w..16w+15, 12 key tiles) ----
    f32x4 accs[12];
    {
        const bf16x8 a0 = *(const bf16x8*)&Qs[(w * 16 + l16) * AKS + g16 * 8];
        const bf16x8 a1 = *(const bf16x8*)&Qs[(w * 16 + l16) * AKS + 32 + g16 * 8];
#pragma unroll
        for (int t = 0; t < 12; ++t) {
            const bf16x8 b0 = *(const bf16x8*)&Ks[(t * 16 + l16) * AKS + g16 * 8];
            const bf16x8 b1 = *(const bf16x8*)&Ks[(t * 16 + l16) * AKS + 32 + g16 * 8];
            f32x4 c = {};
            c = __builtin_amdgcn_mfma_f32_16x16x32_bf16(a0, b0, c, 0, 0, 0);
            c = __builtin_amdgcn_mfma_f32_16x16x32_bf16(a1, b1, c, 0, 0, 0);
            accs[t] = c;
        }
    }

    // ---- softmax in registers ----
    bool mk[12];
    int  jj[12];
#pragma unroll
    for (int t = 0; t < 12; ++t) {
        jj[t] = klo + t * 16 + l16;
        mk[t] = smask[b * 1024 + jj[t]] > 0;
    }

    float rs[4];
#pragma unroll
    for (int r = 0; r < 4; ++r) {
        const int i = qlo + 16 * w + g16 * 4 + r;
        float mx = -1e30f;
#pragma unroll
        for (int t = 0; t < 12; ++t) {
            const bool val = mk[t] && (jj[t] >= i - CB_) && (jj[t] <= i);
            mx = fmaxf(mx, val ? accs[t][r] : -1e30f);
        }
        mx = fmaxf(mx, __shfl_xor(mx, 1));
        mx = fmaxf(mx, __shfl_xor(mx, 2));
        mx = fmaxf(mx, __shfl_xor(mx, 4));
        mx = fmaxf(mx, __shfl_xor(mx, 8));
        float sum = 0.0f;
#pragma unroll
        for (int t = 0; t < 12; ++t) {
            const bool val = mk[t] && (jj[t] >= i - CB_) && (jj[t] <= i);
            const float p = val ? __expf(accs[t][r] - mx) : 0.0f;
            accs[t][r] = p;
            sum += p;
        }
        sum += __shfl_xor(sum, 1);
        sum += __shfl_xor(sum, 2);
        sum += __shfl_xor(sum, 4);
        sum += __shfl_xor(sum, 8);
        rs[r] = 1.0f / sum;
    }

    // ---- P -> LDS (bf16, row-major, A-frag friendly) ----
#pragma unroll
    for (int t = 0; t < 12; ++t)
#pragma unroll
        for (int r = 0; r < 4; ++r)
            Pb[(16 * w + g16 * 4 + r) * AVS + t * 16 + l16] = f2bf(accs[t][r]);

    // ---- O = P @ V ----
#pragma unroll
    for (int nt = 0; nt < 4; ++nt) {
        f32x4 acco = {};
#pragma unroll
        for (int ks = 0; ks < 6; ++ks) {
            const bf16x8 a = *(const bf16x8*)&Pb[(16 * w + l16) * AVS + ks * 32 + g16 * 8];
            const bf16x8 bb = *(const bf16x8*)&Vt[(nt * 16 + l16) * AVS + ks * 32 + g16 * 8];
            acco = __builtin_amdgcn_mfma_f32_16x16x32_bf16(a, bb, acco, 0, 0, 0);
        }
#pragma unroll
        for (int r = 0; r < 4; ++r) {
            const int qrow = 16 * w + g16 * 4 + r;
            o[((size_t)(b * 1024 + qlo + qrow)) * 512 + h * 64 + nt * 16 + l16] =
                f2bf(acco[r] * rs[r]);
        }
    }
}

// ---------------------------------------------------------------------------
extern "C" void kernel_launch(void* const* d_in, const int* in_sizes, int n_in,
                              void* d_out, int out_size, void* d_ws, size_t ws_size,
                              hipStream_t stream)
{
    const float* spikes  = (const float*)d_in[0];
    const int*   smask   = (const int*)d_in[1];
    const int*   ts      = (const int*)d_in[2];
    const float* embed_w = (const float*)d_in[3];
    const float* embed_b = (const float*)d_in[4];
    const float* proj_w  = (const float*)d_in[5];
    const float* proj_b  = (const float*)d_in[6];
    const float* ln1_g   = (const float*)d_in[7];
    const float* ln1_b   = (const float*)d_in[8];
    const float* Wq      = (const float*)d_in[9];
    const float* bq      = (const float*)d_in[10];
    const float* Wk      = (const float*)d_in[11];
    const float* bk      = (const float*)d_in[12];
    const float* Wv      = (const float*)d_in[13];
    const float* bv      = (const float*)d_in[14];
    const float* Wo      = (const float*)d_in[15];
    const float* bo      = (const float*)d_in[16];
    const float* ln2_g   = (const float*)d_in[17];
    const float* ln2_b   = (const float*)d_in[18];
    const float* up_w    = (const float*)d_in[19];
    const float* up_b    = (const float*)d_in[20];
    const float* down_w  = (const float*)d_in[21];
    const float* down_b  = (const float*)d_in[22];

    const int M = B_ * T_;  // 4096

    char* p = (char*)d_ws;
    float* x = (float*)p;                       p += (size_t)M * H_ * 4;
    unsigned short* qb  = (unsigned short*)p;   p += (size_t)M * H_ * 2;
    unsigned short* kb  = (unsigned short*)p;   p += (size_t)M * H_ * 2;
    unsigned short* vTb = (unsigned short*)p;   p += (size_t)M * H_ * 2;
    unsigned short* hbf = (unsigned short*)p;   p += (size_t)M * H_ * 2;
    unsigned short* obf = (unsigned short*)p;   p += (size_t)M * H_ * 2;
    unsigned short* ibf = (unsigned short*)p;   p += (size_t)M * INTER_ * 2;
    unsigned short* tbf = (unsigned short*)p;   p += (size_t)M * D_ * 2;
    unsigned short* spbf  = (unsigned short*)p; p += (size_t)M * C_ * 2;
    unsigned short* embT  = (unsigned short*)p; p += (size_t)D_ * C_ * 2;
    unsigned short* projT = (unsigned short*)p; p += (size_t)H_ * D_ * 2;
    unsigned short* qkvT  = (unsigned short*)p; p += (size_t)L_ * 3 * H_ * H_ * 2;
    unsigned short* woT   = (unsigned short*)p; p += (size_t)L_ * H_ * H_ * 2;
    unsigned short* upT   = (unsigned short*)p; p += (size_t)L_ * INTER_ * H_ * 2;
    unsigned short* downT = (unsigned short*)p; p += (size_t)L_ * H_ * INTER_ * 2;

    // ---- prologue ----
    conv_k<<<(M * C_) / 1024, 256, 0, stream>>>(spikes, spbf);
    tconv_k<<<dim3(D_ / 64, C_ / 64, 1), 256, 0, stream>>>(embed_w, embT, C_, D_, 0, 0);
    tconv_k<<<dim3(H_ / 64, D_ / 64, 1), 256, 0, stream>>>(proj_w, projT, D_, H_, 0, 0);
    tconv_k<<<dim3(H_ / 64, H_ / 64, L_), 256, 0, stream>>>(
        Wq, qkvT,               H_, H_, (long)H_ * H_, (long)3 * H_ * H_);
    tconv_k<<<dim3(H_ / 64, H_ / 64, L_), 256, 0, stream>>>(
        Wk, qkvT + H_ * H_,     H_, H_, (long)H_ * H_, (long)3 * H_ * H_);
    tconv_k<<<dim3(H_ / 64, H_ / 64, L_), 256, 0, stream>>>(
        Wv, qkvT + 2 * H_ * H_, H_, H_, (long)H_ * H_, (long)3 * H_ * H_);
    tconv_k<<<dim3(H_ / 64, H_ / 64, L_), 256, 0, stream>>>(
        Wo, woT, H_, H_, (long)H_ * H_, (long)H_ * H_);
    tconv_k<<<dim3(INTER_ / 64, H_ / 64, L_), 256, 0, stream>>>(
        up_w, upT, H_, INTER_, (long)H_ * INTER_, (long)INTER_ * H_);
    tconv_k<<<dim3(H_ / 64, INTER_ / 64, L_), 256, 0, stream>>>(
        down_w, downT, INTER_, H_, (long)INTER_ * H_, (long)H_ * INTER_);

    // ---- embedding ----
    mm_k<1, 0, 1, 0><<<dim3(D_ / 128, M / 128), 256, 0, stream>>>(
        spbf, embT, embed_b, nullptr, nullptr, nullptr, nullptr,
        tbf, nullptr, nullptr, M, D_, C_);
    mm_k<0, 0, 0, 0><<<dim3(H_ / 128, M / 128), 256, 0, stream>>>(
        tbf, projT, proj_b, nullptr, nullptr, nullptr, nullptr,
        x, nullptr, nullptr, M, H_, D_);

    for (int l = 0; l < L_; ++l) {
        const unsigned short* qkvT_l = qkvT + (size_t)l * 3 * H_ * H_;
        const unsigned short* woT_l  = woT  + (size_t)l * H_ * H_;
        const unsigned short* upT_l  = upT  + (size_t)l * INTER_ * H_;
        const unsigned short* dnT_l  = downT + (size_t)l * H_ * INTER_;

        ln_k<<<M, 256, 0, stream>>>(x, ln1_g + l * H_, ln1_b + l * H_, hbf);

        // fused QKV + bias + RoPE -> qb, kb, vTb (all bf16)
        mm_k<0, 0, 1, 1><<<dim3((3 * H_) / 128, M / 128), 256, 0, stream>>>(
            hbf, qkvT_l, bq + l * H_, bk + l * H_, bv + l * H_, nullptr, ts,
            qb, kb, vTb, M, 3 * H_, H_);

        attn_k<<<B_ * NH_ * (T_ / 64), 256, 0, stream>>>(qb, kb, vTb, smask, obf);

        mm_k<0, 1, 0, 0><<<dim3(H_ / 128, M / 128), 256, 0, stream>>>(
            obf, woT_l, bo + l * H_, nullptr, nullptr, x, nullptr,
            x, nullptr, nullptr, M, H_, H_);

        ln_k<<<M, 256, 0, stream>>>(x, ln2_g + l * H_, ln2_b + l * H_, hbf);

        mm_k<1, 0, 1, 0><<<dim3(INTER_ / 128, M / 128), 256, 0, stream>>>(
            hbf, upT_l, up_b + l * INTER_, nullptr, nullptr, nullptr, nullptr,
            ibf, nullptr, nullptr, M, INTER_, H_);

        float* dst = (l == L_ - 1) ? (float*)d_out : x;
        mm_k<0, 1, 0, 0><<<dim3(H_ / 128, M / 128), 256, 0, stream>>>(
            ibf, dnT_l, down_b + l * H_, nullptr, nullptr, x, nullptr,
            dst, nullptr, nullptr, M, H_, INTER_);
    }
}

// Round 5
// 1310.527 us; speedup vs baseline: 1.0070x; 1.0070x over previous
//
#include <hip/hip_runtime.h>
#include <math.h>

// Problem dims (fixed)
#define B_ 4
#define T_ 1024
#define C_ 256
#define D_ 256
#define H_ 512
#define NH_ 8
#define HD_ 64
#define INTER_ 2048
#define L_ 4
#define CB_ 128   // context_backward; context_forward = 0

typedef short bf16x8 __attribute__((ext_vector_type(8)));
typedef float f32x4 __attribute__((ext_vector_type(4)));

__device__ __forceinline__ float gelu_exact(float x) {
    return 0.5f * x * (1.0f + erff(x * 0.70710678118654752f));
}

// fp32 -> bf16 round-to-nearest-even
__device__ __forceinline__ unsigned short f2bf(float f) {
    unsigned u = __float_as_uint(f);
    u += 0x7fffu + ((u >> 16) & 1u);
    return (unsigned short)(u >> 16);
}

// ---------------------------------------------------------------------------
// bf16 MFMA GEMM: out[M,N] = epi(A[M,K](bf16) @ BT[N,K](bf16)^T + bias)
// 128x128 tile, 256 threads (4 waves 2x2), each wave 4x4 of 16x16x32 MFMA.
// BK=32, global_load_lds width-16 staging.
// bf16 outputs (OBF/SPLIT) go through an in-LDS transpose so global stores
// are ushort4 with 32B runs per 4-lane group (L2-merge friendly; the round-4
// scatter/scalar pattern caused ~29x HBM write amplification).
// SPLIT=1: QKV mode. N=1536 (q 0-511, k 512-1023, v 1024-1535). Epilogue
// applies bias (+RoPE on q,k; q scaled 0.125); writes bf16 [M,512] each.
// ---------------------------------------------------------------------------
template<int ACT, int RES, int OBF, int SPLIT>
__global__ __launch_bounds__(256) void mm_k(
    const unsigned short* __restrict__ A, const unsigned short* __restrict__ BT,
    const float* __restrict__ b0, const float* __restrict__ b1,
    const float* __restrict__ b2,
    const float* res, const int* __restrict__ ts,
    void* o0, void* o1, void* o2,
    const int M, const int N, const int K)
{
    __shared__ unsigned short As[128 * 32];
    __shared__ unsigned short Bs[128 * 32];

    const int tid  = threadIdx.x;
    const int lane = tid & 63;
    const int w    = tid >> 6;
    const int m0   = blockIdx.y * 128;
    const int n0   = blockIdx.x * 128;
    const int wm   = (w >> 1) * 64;
    const int wn   = (w & 1) * 64;
    const int l16  = lane & 15;
    const int g16  = lane >> 4;
    const int fk   = g16 * 8;

    f32x4 acc[4][4] = {};

    const int c0 = (w << 6) + lane;
    const int c1 = c0 + 256;

    const unsigned short* Abase = A  + (size_t)m0 * K;
    const unsigned short* Bbase = BT + (size_t)n0 * K;

    for (int k0 = 0; k0 < K; k0 += 32) {
        __syncthreads();
        const unsigned short* ga0 = Abase + (size_t)(c0 >> 2) * K + k0 + (c0 & 3) * 8;
        const unsigned short* ga1 = Abase + (size_t)(c1 >> 2) * K + k0 + (c1 & 3) * 8;
        __builtin_amdgcn_global_load_lds(
            (const __attribute__((address_space(1))) unsigned*)ga0,
            (__attribute__((address_space(3))) unsigned*)(As + (size_t)(w << 6) * 8), 16, 0, 0);
        __builtin_amdgcn_global_load_lds(
            (const __attribute__((address_space(1))) unsigned*)ga1,
            (__attribute__((address_space(3))) unsigned*)(As + (size_t)(256 + (w << 6)) * 8), 16, 0, 0);
        const unsigned short* gb0 = Bbase + (size_t)(c0 >> 2) * K + k0 + (c0 & 3) * 8;
        const unsigned short* gb1 = Bbase + (size_t)(c1 >> 2) * K + k0 + (c1 & 3) * 8;
        __builtin_amdgcn_global_load_lds(
            (const __attribute__((address_space(1))) unsigned*)gb0,
            (__attribute__((address_space(3))) unsigned*)(Bs + (size_t)(w << 6) * 8), 16, 0, 0);
        __builtin_amdgcn_global_load_lds(
            (const __attribute__((address_space(1))) unsigned*)gb1,
            (__attribute__((address_space(3))) unsigned*)(Bs + (size_t)(256 + (w << 6)) * 8), 16, 0, 0);
        __syncthreads();

        bf16x8 a[4], b[4];
#pragma unroll
        for (int t = 0; t < 4; ++t)
            a[t] = *(const bf16x8*)&As[(wm + t * 16 + l16) * 32 + fk];
#pragma unroll
        for (int t = 0; t < 4; ++t)
            b[t] = *(const bf16x8*)&Bs[(wn + t * 16 + l16) * 32 + fk];
#pragma unroll
        for (int i = 0; i < 4; ++i)
#pragma unroll
            for (int j = 0; j < 4; ++j)
                acc[i][j] = __builtin_amdgcn_mfma_f32_16x16x32_bf16(a[i], b[j], acc[i][j], 0, 0, 0);
    }

    if (OBF || SPLIT) {
        // bf16 output: per-i-tile in-LDS transpose (reuse As/Bs), then
        // ushort4 stores (4-lane groups = 32B runs, 4 runs = 128B strip).
        __syncthreads();
        unsigned short* Eb = (w < 2) ? (As + w * 1152) : (Bs + (w - 2) * 1152);
        const int row16 = lane >> 2;   // output row within 16-row tile
        const int cg    = lane & 3;    // 4-lane col group

        const int gnb   = n0 + wn;
        const int which = SPLIT ? (gnb >> 9) : 0;
        const int lnb   = SPLIT ? (gnb & 511) : gnb;
        const int ldo   = SPLIT ? 512 : N;
        unsigned short* oo = SPLIT
            ? ((which == 0) ? (unsigned short*)o0 : (which == 1) ? (unsigned short*)o1 : (unsigned short*)o2)
            : (unsigned short*)o0;
        const float* bb = SPLIT ? ((which == 0) ? b0 : (which == 1) ? b1 : b2) : b0;

#pragma unroll
        for (int i = 0; i < 4; ++i) {
            const int gmb = m0 + wm + i * 16 + g16 * 4;
            if (SPLIT && which < 2) {
                // RoPE on pairs (d, d+32); q additionally scaled by 0.125
#pragma unroll
                for (int j = 0; j < 2; ++j) {
                    const int d = j * 16 + l16;
                    const float freq = __expf(-0.2878231366242558f * (float)d);
                    const float bv1 = bb[lnb + d];
                    const float bv2 = bb[lnb + d + 32];
#pragma unroll
                    for (int r = 0; r < 4; ++r) {
                        const float ang = (float)ts[gmb + r] * freq;
                        const float cc = cosf(ang);
                        const float ss = sinf(ang);
                        float v1 = acc[i][j][r] + bv1;
                        float v2 = acc[i][j + 2][r] + bv2;
                        float r1 = v1 * cc - v2 * ss;
                        float r2 = v2 * cc + v1 * ss;
                        if (which == 0) { r1 *= 0.125f; r2 *= 0.125f; }
                        Eb[(g16 * 4 + r) * 72 + d]      = f2bf(r1);
                        Eb[(g16 * 4 + r) * 72 + d + 32] = f2bf(r2);
                    }
                }
            } else {
#pragma unroll
                for (int j = 0; j < 4; ++j) {
                    const float bv = bb[lnb + j * 16 + l16];
#pragma unroll
                    for (int r = 0; r < 4; ++r) {
                        float cv = acc[i][j][r] + bv;
                        if (ACT) cv = gelu_exact(cv);
                        Eb[(g16 * 4 + r) * 72 + j * 16 + l16] = f2bf(cv);
                    }
                }
            }
            const int grow0 = m0 + wm + i * 16 + row16;
#pragma unroll
            for (int s = 0; s < 4; ++s) {
                ushort4 t4 = *(const ushort4*)&Eb[row16 * 72 + s * 16 + cg * 4];
                *(ushort4*)&oo[(size_t)grow0 * ldo + lnb + s * 16 + cg * 4] = t4;
            }
        }
        return;
    }

    // fp32 output epilogue (scalar 4B stores = full 64B runs per 16 lanes)
#pragma unroll
    for (int i = 0; i < 4; ++i) {
        const int gmb = m0 + wm + i * 16 + g16 * 4;
#pragma unroll
        for (int j = 0; j < 4; ++j) {
            const int gn = n0 + wn + j * 16 + l16;
            const float bv = b0[gn];
#pragma unroll
            for (int r = 0; r < 4; ++r) {
                float cv = acc[i][j][r] + bv;
                if (ACT) cv = gelu_exact(cv);
                if (RES) cv += res[(size_t)(gmb + r) * 512 + gn];
                ((float*)o0)[(size_t)(gmb + r) * N + gn] = cv;
            }
        }
    }
}

// ---------------------------------------------------------------------------
// Transpose + fp32->bf16: src [R,Cc] fp32 -> dst [Cc,R] bf16. 64x64 tiles.
// ---------------------------------------------------------------------------
__global__ __launch_bounds__(256) void tconv_k(
    const float* __restrict__ src, unsigned short* __restrict__ dst,
    int R, int Cc, long slay, long dlay)
{
    __shared__ float tile[64][65];
    const int t = threadIdx.x;
    src += (size_t)blockIdx.z * slay;
    dst += (size_t)blockIdx.z * dlay;
    const int r0 = blockIdx.y * 64, c0 = blockIdx.x * 64;
    const int tr = t >> 4, tc = (t & 15) * 4;
#pragma unroll
    for (int i = 0; i < 4; ++i) {
        float4 v = *(const float4*)&src[(size_t)(r0 + tr + i * 16) * Cc + c0 + tc];
        tile[tr + i * 16][tc + 0] = v.x;
        tile[tr + i * 16][tc + 1] = v.y;
        tile[tr + i * 16][tc + 2] = v.z;
        tile[tr + i * 16][tc + 3] = v.w;
    }
    __syncthreads();
#pragma unroll
    for (int i = 0; i < 4; ++i) {
        const int n = tr + i * 16;
        ushort4 o;
        o.x = f2bf(tile[tc + 0][n]);
        o.y = f2bf(tile[tc + 1][n]);
        o.z = f2bf(tile[tc + 2][n]);
        o.w = f2bf(tile[tc + 3][n]);
        *(ushort4*)&dst[(size_t)(c0 + n) * R + r0 + tc] = o;
    }
}

// elementwise fp32 -> bf16
__global__ __launch_bounds__(256) void conv_k(
    const float* __restrict__ src, unsigned short* __restrict__ dst)
{
    const int i = (blockIdx.x * 256 + threadIdx.x) * 4;
    float4 v = *(const float4*)&src[i];
    ushort4 o = {f2bf(v.x), f2bf(v.y), f2bf(v.z), f2bf(v.w)};
    *(ushort4*)&dst[i] = o;
}

// ---------------------------------------------------------------------------
// LayerNorm over H=512, bf16 output.
// ---------------------------------------------------------------------------
__global__ __launch_bounds__(256) void ln_k(
    const float* __restrict__ x, const float* __restrict__ g,
    const float* __restrict__ b, unsigned short* __restrict__ out)
{
    const int row = blockIdx.x;
    const int tid = threadIdx.x;
    const float* xr = x + (size_t)row * H_;

    float v0 = xr[tid];
    float v1 = xr[tid + 256];

    float s = v0 + v1;
#pragma unroll
    for (int off = 32; off; off >>= 1) s += __shfl_xor(s, off);

    __shared__ float red[4];
    const int wave = tid >> 6;
    if ((tid & 63) == 0) red[wave] = s;
    __syncthreads();
    const float mean = (red[0] + red[1] + red[2] + red[3]) * (1.0f / (float)H_);

    const float d0 = v0 - mean, d1 = v1 - mean;
    float q = d0 * d0 + d1 * d1;
#pragma unroll
    for (int off = 32; off; off >>= 1) q += __shfl_xor(q, off);
    __syncthreads();
    if ((tid & 63) == 0) red[wave] = q;
    __syncthreads();
    const float var = (red[0] + red[1] + red[2] + red[3]) * (1.0f / (float)H_);
    const float rstd = rsqrtf(var + 1e-5f);

    out[(size_t)row * H_ + tid]       = f2bf(d0 * rstd * g[tid] + b[tid]);
    out[(size_t)row * H_ + tid + 256] = f2bf(d1 * rstd * g[tid + 256] + b[tid + 256]);
}

// ---------------------------------------------------------------------------
// MFMA banded attention. One block per (b, h, 64-query tile); 4 waves.
// Inputs: q,k,v bf16 [B*T,512] (q,k rotated; q pre-scaled by 0.125/sqrt).
// V transposed into LDS during staging (no global transposed buffer).
// S via mfma; softmax in registers; P -> LDS bf16; PV via mfma; output
// vector-stored through Pb (ushort4, 32B runs).
// ---------------------------------------------------------------------------
#define AWIN 192
#define AKS 72    // ushort stride Qs/Ks
#define AVS 200   // ushort stride Vt/Pb

__global__ __launch_bounds__(256) void attn_k(
    const unsigned short* __restrict__ q, const unsigned short* __restrict__ k,
    const unsigned short* __restrict__ v, const int* __restrict__ smask,
    unsigned short* __restrict__ o)
{
    __shared__ unsigned short Qs[64 * AKS];
    __shared__ unsigned short Ks[AWIN * AKS];
    __shared__ unsigned short Vt[64 * AVS];
    __shared__ unsigned short Pb[64 * AVS];

    const int blk = blockIdx.x;
    const int qt = blk & 15;
    const int h  = (blk >> 4) & 7;
    const int b  = blk >> 7;
    const int tid  = threadIdx.x;
    const int lane = tid & 63;
    const int w    = tid >> 6;
    const int l16  = lane & 15;
    const int g16  = lane >> 4;

    const int qlo = qt * 64;
    const int klo = (qlo >= CB_) ? (qlo - CB_) : 0;

    // ---- stage ----
    {
        const unsigned short* gq = q + ((size_t)(b * 1024 + qlo)) * 512 + h * 64;
        for (int c = tid; c < 64 * 16; c += 256) {
            const int row = c >> 4, c4 = (c & 15) * 4;
            *(ushort4*)&Qs[row * AKS + c4] = *(const ushort4*)&gq[(size_t)row * 512 + c4];
        }
        const unsigned short* gk = k + ((size_t)(b * 1024 + klo)) * 512 + h * 64;
        for (int c = tid; c < AWIN * 16; c += 256) {
            const int row = c >> 4, c4 = (c & 15) * 4;
            *(ushort4*)&Ks[row * AKS + c4] = *(const ushort4*)&gk[(size_t)row * 512 + c4];
        }
        // V: coalesced global read, transposed LDS write -> Vt[d][j]
        const unsigned short* gv = v + ((size_t)(b * 1024 + klo)) * 512 + h * 64;
        for (int c = tid; c < AWIN * 16; c += 256) {
            const int row = c >> 4, c4 = (c & 15) * 4;
            ushort4 vv = *(const ushort4*)&gv[(size_t)row * 512 + c4];
            Vt[(c4 + 0) * AVS + row] = vv.x;
            Vt[(c4 + 1) * AVS + row] = vv.y;
            Vt[(c4 + 2) * AVS + row] = vv.z;
            Vt[(c4 + 3) * AVS + row] = vv.w;
        }
    }
    __syncthreads();

    // ---- S = Q @ K^T (wave w: q-rows 16w..16w+15, 12 key tiles) ----
    f32x4 accs[12];
    {
        const bf16x8 a0 = *(const bf16x8*)&Qs[(w * 16 + l16) * AKS + g16 * 8];
        const bf16x8 a1 = *(const bf16x8*)&Qs[(w * 16 + l16) * AKS + 32 + g16 * 8];
#pragma unroll
        for (int t = 0; t < 12; ++t) {
            const bf16x8 b0 = *(const bf16x8*)&Ks[(t * 16 + l16) * AKS + g16 * 8];
            const bf16x8 b1 = *(const bf16x8*)&Ks[(t * 16 + l16) * AKS + 32 + g16 * 8];
            f32x4 c = {};
            c = __builtin_amdgcn_mfma_f32_16x16x32_bf16(a0, b0, c, 0, 0, 0);
            c = __builtin_amdgcn_mfma_f32_16x16x32_bf16(a1, b1, c, 0, 0, 0);
            accs[t] = c;
        }
    }

    // ---- softmax in registers ----
    bool mk[12];
    int  jj[12];
#pragma unroll
    for (int t = 0; t < 12; ++t) {
        jj[t] = klo + t * 16 + l16;
        mk[t] = smask[b * 1024 + jj[t]] > 0;
    }

    float rs[4];
#pragma unroll
    for (int r = 0; r < 4; ++r) {
        const int i = qlo + 16 * w + g16 * 4 + r;
        float mx = -1e30f;
#pragma unroll
        for (int t = 0; t < 12; ++t) {
            const bool val = mk[t] && (jj[t] >= i - CB_) && (jj[t] <= i);
            mx = fmaxf(mx, val ? accs[t][r] : -1e30f);
        }
        mx = fmaxf(mx, __shfl_xor(mx, 1));
        mx = fmaxf(mx, __shfl_xor(mx, 2));
        mx = fmaxf(mx, __shfl_xor(mx, 4));
        mx = fmaxf(mx, __shfl_xor(mx, 8));
        float sum = 0.0f;
#pragma unroll
        for (int t = 0; t < 12; ++t) {
            const bool val = mk[t] && (jj[t] >= i - CB_) && (jj[t] <= i);
            const float p = val ? __expf(accs[t][r] - mx) : 0.0f;
            accs[t][r] = p;
            sum += p;
        }
        sum += __shfl_xor(sum, 1);
        sum += __shfl_xor(sum, 2);
        sum += __shfl_xor(sum, 4);
        sum += __shfl_xor(sum, 8);
        rs[r] = 1.0f / sum;
    }

    // ---- P -> LDS (bf16, row-major, A-frag friendly) ----
#pragma unroll
    for (int t = 0; t < 12; ++t)
#pragma unroll
        for (int r = 0; r < 4; ++r)
            Pb[(16 * w + g16 * 4 + r) * AVS + t * 16 + l16] = f2bf(accs[t][r]);

    // ---- O = P @ V (accumulate all nt first) ----
    f32x4 acco[4];
#pragma unroll
    for (int nt = 0; nt < 4; ++nt) {
        f32x4 c = {};
#pragma unroll
        for (int ks = 0; ks < 6; ++ks) {
            const bf16x8 a = *(const bf16x8*)&Pb[(16 * w + l16) * AVS + ks * 32 + g16 * 8];
            const bf16x8 bb = *(const bf16x8*)&Vt[(nt * 16 + l16) * AVS + ks * 32 + g16 * 8];
            c = __builtin_amdgcn_mfma_f32_16x16x32_bf16(a, bb, c, 0, 0, 0);
        }
        acco[nt] = c;
    }

    // ---- stage O into Pb cols 0..63, then vector store ----
    __syncthreads();   // all waves done reading Pb rows (A-frags)
#pragma unroll
    for (int nt = 0; nt < 4; ++nt)
#pragma unroll
        for (int r = 0; r < 4; ++r)
            Pb[(16 * w + g16 * 4 + r) * AVS + nt * 16 + l16] = f2bf(acco[nt][r] * rs[r]);

    const int row16 = lane >> 2, cg = lane & 3;
    const int grow = b * 1024 + qlo + 16 * w + row16;
#pragma unroll
    for (int s = 0; s < 4; ++s) {
        ushort4 t4 = *(const ushort4*)&Pb[(16 * w + row16) * AVS + s * 16 + cg * 4];
        *(ushort4*)&o[(size_t)grow * 512 + h * 64 + s * 16 + cg * 4] = t4;
    }
}

// ---------------------------------------------------------------------------
extern "C" void kernel_launch(void* const* d_in, const int* in_sizes, int n_in,
                              void* d_out, int out_size, void* d_ws, size_t ws_size,
                              hipStream_t stream)
{
    const float* spikes  = (const float*)d_in[0];
    const int*   smask   = (const int*)d_in[1];
    const int*   ts      = (const int*)d_in[2];
    const float* embed_w = (const float*)d_in[3];
    const float* embed_b = (const float*)d_in[4];
    const float* proj_w  = (const float*)d_in[5];
    const float* proj_b  = (const float*)d_in[6];
    const float* ln1_g   = (const float*)d_in[7];
    const float* ln1_b   = (const float*)d_in[8];
    const float* Wq      = (const float*)d_in[9];
    const float* bq      = (const float*)d_in[10];
    const float* Wk      = (const float*)d_in[11];
    const float* bk      = (const float*)d_in[12];
    const float* Wv      = (const float*)d_in[13];
    const float* bv      = (const float*)d_in[14];
    const float* Wo      = (const float*)d_in[15];
    const float* bo      = (const float*)d_in[16];
    const float* ln2_g   = (const float*)d_in[17];
    const float* ln2_b   = (const float*)d_in[18];
    const float* up_w    = (const float*)d_in[19];
    const float* up_b    = (const float*)d_in[20];
    const float* down_w  = (const float*)d_in[21];
    const float* down_b  = (const float*)d_in[22];

    const int M = B_ * T_;  // 4096

    char* p = (char*)d_ws;
    float* x = (float*)p;                       p += (size_t)M * H_ * 4;
    unsigned short* qb  = (unsigned short*)p;   p += (size_t)M * H_ * 2;
    unsigned short* kb  = (unsigned short*)p;   p += (size_t)M * H_ * 2;
    unsigned short* vb  = (unsigned short*)p;   p += (size_t)M * H_ * 2;
    unsigned short* hbf = (unsigned short*)p;   p += (size_t)M * H_ * 2;
    unsigned short* obf = (unsigned short*)p;   p += (size_t)M * H_ * 2;
    unsigned short* ibf = (unsigned short*)p;   p += (size_t)M * INTER_ * 2;
    unsigned short* tbf = (unsigned short*)p;   p += (size_t)M * D_ * 2;
    unsigned short* spbf  = (unsigned short*)p; p += (size_t)M * C_ * 2;
    unsigned short* embT  = (unsigned short*)p; p += (size_t)D_ * C_ * 2;
    unsigned short* projT = (unsigned short*)p; p += (size_t)H_ * D_ * 2;
    unsigned short* qkvT  = (unsigned short*)p; p += (size_t)L_ * 3 * H_ * H_ * 2;
    unsigned short* woT   = (unsigned short*)p; p += (size_t)L_ * H_ * H_ * 2;
    unsigned short* upT   = (unsigned short*)p; p += (size_t)L_ * INTER_ * H_ * 2;
    unsigned short* downT = (unsigned short*)p; p += (size_t)L_ * H_ * INTER_ * 2;

    // ---- prologue ----
    conv_k<<<(M * C_) / 1024, 256, 0, stream>>>(spikes, spbf);
    tconv_k<<<dim3(D_ / 64, C_ / 64, 1), 256, 0, stream>>>(embed_w, embT, C_, D_, 0, 0);
    tconv_k<<<dim3(H_ / 64, D_ / 64, 1), 256, 0, stream>>>(proj_w, projT, D_, H_, 0, 0);
    tconv_k<<<dim3(H_ / 64, H_ / 64, L_), 256, 0, stream>>>(
        Wq, qkvT,               H_, H_, (long)H_ * H_, (long)3 * H_ * H_);
    tconv_k<<<dim3(H_ / 64, H_ / 64, L_), 256, 0, stream>>>(
        Wk, qkvT + H_ * H_,     H_, H_, (long)H_ * H_, (long)3 * H_ * H_);
    tconv_k<<<dim3(H_ / 64, H_ / 64, L_), 256, 0, stream>>>(
        Wv, qkvT + 2 * H_ * H_, H_, H_, (long)H_ * H_, (long)3 * H_ * H_);
    tconv_k<<<dim3(H_ / 64, H_ / 64, L_), 256, 0, stream>>>(
        Wo, woT, H_, H_, (long)H_ * H_, (long)H_ * H_);
    tconv_k<<<dim3(INTER_ / 64, H_ / 64, L_), 256, 0, stream>>>(
        up_w, upT, H_, INTER_, (long)H_ * INTER_, (long)INTER_ * H_);
    tconv_k<<<dim3(H_ / 64, INTER_ / 64, L_), 256, 0, stream>>>(
        down_w, downT, INTER_, H_, (long)INTER_ * H_, (long)H_ * INTER_);

    // ---- embedding ----
    mm_k<1, 0, 1, 0><<<dim3(D_ / 128, M / 128), 256, 0, stream>>>(
        spbf, embT, embed_b, nullptr, nullptr, nullptr, nullptr,
        tbf, nullptr, nullptr, M, D_, C_);
    mm_k<0, 0, 0, 0><<<dim3(H_ / 128, M / 128), 256, 0, stream>>>(
        tbf, projT, proj_b, nullptr, nullptr, nullptr, nullptr,
        x, nullptr, nullptr, M, H_, D_);

    for (int l = 0; l < L_; ++l) {
        const unsigned short* qkvT_l = qkvT + (size_t)l * 3 * H_ * H_;
        const unsigned short* woT_l  = woT  + (size_t)l * H_ * H_;
        const unsigned short* upT_l  = upT  + (size_t)l * INTER_ * H_;
        const unsigned short* dnT_l  = downT + (size_t)l * H_ * INTER_;

        ln_k<<<M, 256, 0, stream>>>(x, ln1_g + l * H_, ln1_b + l * H_, hbf);

        // fused QKV + bias + RoPE -> qb, kb, vb (all bf16 [M,512])
        mm_k<0, 0, 1, 1><<<dim3((3 * H_) / 128, M / 128), 256, 0, stream>>>(
            hbf, qkvT_l, bq + l * H_, bk + l * H_, bv + l * H_, nullptr, ts,
            qb, kb, vb, M, 3 * H_, H_);

        attn_k<<<B_ * NH_ * (T_ / 64), 256, 0, stream>>>(qb, kb, vb, smask, obf);

        mm_k<0, 1, 0, 0><<<dim3(H_ / 128, M / 128), 256, 0, stream>>>(
            obf, woT_l, bo + l * H_, nullptr, nullptr, x, nullptr,
            x, nullptr, nullptr, M, H_, H_);

        ln_k<<<M, 256, 0, stream>>>(x, ln2_g + l * H_, ln2_b + l * H_, hbf);

        mm_k<1, 0, 1, 0><<<dim3(INTER_ / 128, M / 128), 256, 0, stream>>>(
            hbf, upT_l, up_b + l * INTER_, nullptr, nullptr, nullptr, nullptr,
            ibf, nullptr, nullptr, M, INTER_, H_);

        float* dst = (l == L_ - 1) ? (float*)d_out : x;
        mm_k<0, 1, 0, 0><<<dim3(H_ / 128, M / 128), 256, 0, stream>>>(
            ibf, dnT_l, down_b + l * H_, nullptr, nullptr, x, nullptr,
            dst, nullptr, nullptr, M, H_, INTER_);
    }
}

// Round 7
// 849.258 us; speedup vs baseline: 1.5540x; 1.5431x over previous
//
#include <hip/hip_runtime.h>
#include <math.h>

// Problem dims (fixed)
#define B_ 4
#define T_ 1024
#define C_ 256
#define D_ 256
#define H_ 512
#define NH_ 8
#define HD_ 64
#define INTER_ 2048
#define L_ 4
#define CB_ 128   // context_backward; context_forward = 0

typedef short bf16x8 __attribute__((ext_vector_type(8)));
typedef float f32x4 __attribute__((ext_vector_type(4)));

__device__ __forceinline__ float gelu_exact(float x) {
    return 0.5f * x * (1.0f + erff(x * 0.70710678118654752f));
}

// fp32 -> bf16 round-to-nearest-even
__device__ __forceinline__ unsigned short f2bf(float f) {
    unsigned u = __float_as_uint(f);
    u += 0x7fffu + ((u >> 16) & 1u);
    return (unsigned short)(u >> 16);
}
__device__ __forceinline__ float bf2f(unsigned short h) {
    return __uint_as_float((unsigned)h << 16);
}

// ---------------------------------------------------------------------------
// bf16 MFMA GEMM: out[M,N] = epi(A[M,K](bf16) @ BT[N,K](bf16)^T + bias)
// 128x128 tile, 256 threads (4 waves 2x2), each wave 4x4 of 16x16x32 MFMA.
// BK=32, global_load_lds width-16 staging.
// bf16 outputs go through an in-LDS transpose -> ushort4 stores.
// SPLIT=1: QKV. N=1536 (q 0-511, k 512-1023, v 1024-1535); routes output and
// bias by strip; q scaled 0.125. NO trig here (RoPE is a separate kernel —
// libm cosf/sinf slow-path in the epilogue was latency-disaster, R4/R5).
// ---------------------------------------------------------------------------
template<int ACT, int RES, int OBF, int SPLIT>
__global__ __launch_bounds__(256) void mm_k(
    const unsigned short* __restrict__ A, const unsigned short* __restrict__ BT,
    const float* __restrict__ b0, const float* __restrict__ b1,
    const float* __restrict__ b2,
    const float* res,
    void* o0, void* o1, void* o2,
    const int M, const int N, const int K)
{
    __shared__ unsigned short As[128 * 32];
    __shared__ unsigned short Bs[128 * 32];

    const int tid  = threadIdx.x;
    const int lane = tid & 63;
    const int w    = tid >> 6;
    const int m0   = blockIdx.y * 128;
    const int n0   = blockIdx.x * 128;
    const int wm   = (w >> 1) * 64;
    const int wn   = (w & 1) * 64;
    const int l16  = lane & 15;
    const int g16  = lane >> 4;
    const int fk   = g16 * 8;

    f32x4 acc[4][4] = {};

    const int c0 = (w << 6) + lane;
    const int c1 = c0 + 256;

    const unsigned short* Abase = A  + (size_t)m0 * K;
    const unsigned short* Bbase = BT + (size_t)n0 * K;

    for (int k0 = 0; k0 < K; k0 += 32) {
        __syncthreads();
        const unsigned short* ga0 = Abase + (size_t)(c0 >> 2) * K + k0 + (c0 & 3) * 8;
        const unsigned short* ga1 = Abase + (size_t)(c1 >> 2) * K + k0 + (c1 & 3) * 8;
        __builtin_amdgcn_global_load_lds(
            (const __attribute__((address_space(1))) unsigned*)ga0,
            (__attribute__((address_space(3))) unsigned*)(As + (size_t)(w << 6) * 8), 16, 0, 0);
        __builtin_amdgcn_global_load_lds(
            (const __attribute__((address_space(1))) unsigned*)ga1,
            (__attribute__((address_space(3))) unsigned*)(As + (size_t)(256 + (w << 6)) * 8), 16, 0, 0);
        const unsigned short* gb0 = Bbase + (size_t)(c0 >> 2) * K + k0 + (c0 & 3) * 8;
        const unsigned short* gb1 = Bbase + (size_t)(c1 >> 2) * K + k0 + (c1 & 3) * 8;
        __builtin_amdgcn_global_load_lds(
            (const __attribute__((address_space(1))) unsigned*)gb0,
            (__attribute__((address_space(3))) unsigned*)(Bs + (size_t)(w << 6) * 8), 16, 0, 0);
        __builtin_amdgcn_global_load_lds(
            (const __attribute__((address_space(1))) unsigned*)gb1,
            (__attribute__((address_space(3))) unsigned*)(Bs + (size_t)(256 + (w << 6)) * 8), 16, 0, 0);
        __syncthreads();

        bf16x8 a[4], b[4];
#pragma unroll
        for (int t = 0; t < 4; ++t)
            a[t] = *(const bf16x8*)&As[(wm + t * 16 + l16) * 32 + fk];
#pragma unroll
        for (int t = 0; t < 4; ++t)
            b[t] = *(const bf16x8*)&Bs[(wn + t * 16 + l16) * 32 + fk];
#pragma unroll
        for (int i = 0; i < 4; ++i)
#pragma unroll
            for (int j = 0; j < 4; ++j)
                acc[i][j] = __builtin_amdgcn_mfma_f32_16x16x32_bf16(a[i], b[j], acc[i][j], 0, 0, 0);
    }

    if (OBF || SPLIT) {
        // bf16 output: per-i-tile in-LDS transpose (reuse As/Bs), then
        // ushort4 stores (4-lane groups = 32B runs).
        __syncthreads();
        unsigned short* Eb = (w < 2) ? (As + w * 1152) : (Bs + (w - 2) * 1152);
        const int row16 = lane >> 2;
        const int cg    = lane & 3;

        const int gnb   = n0 + wn;
        const int which = SPLIT ? (gnb >> 9) : 0;
        const int lnb   = SPLIT ? (gnb & 511) : gnb;
        const int ldo   = SPLIT ? 512 : N;
        unsigned short* oo = SPLIT
            ? ((which == 0) ? (unsigned short*)o0 : (which == 1) ? (unsigned short*)o1 : (unsigned short*)o2)
            : (unsigned short*)o0;
        const float* bb = SPLIT ? ((which == 0) ? b0 : (which == 1) ? b1 : b2) : b0;
        const float scale = (SPLIT && which == 0) ? 0.125f : 1.0f;

#pragma unroll
        for (int i = 0; i < 4; ++i) {
#pragma unroll
            for (int j = 0; j < 4; ++j) {
                const float bv = bb[lnb + j * 16 + l16];
#pragma unroll
                for (int r = 0; r < 4; ++r) {
                    float cv = acc[i][j][r] + bv;
                    if (ACT) cv = gelu_exact(cv);
                    if (SPLIT) cv *= scale;
                    Eb[(g16 * 4 + r) * 72 + j * 16 + l16] = f2bf(cv);
                }
            }
            const int grow0 = m0 + wm + i * 16 + row16;
#pragma unroll
            for (int s = 0; s < 4; ++s) {
                ushort4 t4 = *(const ushort4*)&Eb[row16 * 72 + s * 16 + cg * 4];
                *(ushort4*)&oo[(size_t)grow0 * ldo + lnb + s * 16 + cg * 4] = t4;
            }
        }
        return;
    }

    // fp32 output epilogue (scalar 4B stores = full 64B runs per 16 lanes)
#pragma unroll
    for (int i = 0; i < 4; ++i) {
        const int gmb = m0 + wm + i * 16 + g16 * 4;
#pragma unroll
        for (int j = 0; j < 4; ++j) {
            const int gn = n0 + wn + j * 16 + l16;
            const float bv = b0[gn];
#pragma unroll
            for (int r = 0; r < 4; ++r) {
                float cv = acc[i][j][r] + bv;
                if (ACT) cv = gelu_exact(cv);
                if (RES) cv += res[(size_t)(gmb + r) * 512 + gn];
                ((float*)o0)[(size_t)(gmb + r) * N + gn] = cv;
            }
        }
    }
}

// ---------------------------------------------------------------------------
// RoPE in-place on bf16 q,k [B*T,512]. Native v_cos/v_sin (fast range
// reduction; rev <= 163 within HW domain; error ~1e-4 << bf16 eps).
// ---------------------------------------------------------------------------
__global__ __launch_bounds__(256) void ropeb_k(
    unsigned short* __restrict__ q, unsigned short* __restrict__ k,
    const int* __restrict__ ts)
{
    const int idx = blockIdx.x * 256 + threadIdx.x;  // B*T*NH*32 total
    const int d  = idx & 31;
    const int nh = (idx >> 5) & (NH_ - 1);
    const int t  = (idx >> 8) & (T_ - 1);
    const int b  = idx >> 18;

    const float freq = __expf(-0.2878231366242558f * (float)d);
    const float ang = (float)ts[b * T_ + t] * freq;
    const float cc = __cosf(ang);
    const float ss = __sinf(ang);

    const size_t base = ((size_t)(b * T_ + t)) * 512 + nh * 64 + d;
    const float q1 = bf2f(q[base]), q2 = bf2f(q[base + 32]);
    q[base]      = f2bf(q1 * cc - q2 * ss);
    q[base + 32] = f2bf(q2 * cc + q1 * ss);
    const float k1 = bf2f(k[base]), k2 = bf2f(k[base + 32]);
    k[base]      = f2bf(k1 * cc - k2 * ss);
    k[base + 32] = f2bf(k2 * cc + k1 * ss);
}

// ---------------------------------------------------------------------------
// Transpose + fp32->bf16: src [R,Cc] fp32 -> dst [Cc,R] bf16. 64x64 tiles.
// ---------------------------------------------------------------------------
__global__ __launch_bounds__(256) void tconv_k(
    const float* __restrict__ src, unsigned short* __restrict__ dst,
    int R, int Cc, long slay, long dlay)
{
    __shared__ float tile[64][65];
    const int t = threadIdx.x;
    src += (size_t)blockIdx.z * slay;
    dst += (size_t)blockIdx.z * dlay;
    const int r0 = blockIdx.y * 64, c0 = blockIdx.x * 64;
    const int tr = t >> 4, tc = (t & 15) * 4;
#pragma unroll
    for (int i = 0; i < 4; ++i) {
        float4 v = *(const float4*)&src[(size_t)(r0 + tr + i * 16) * Cc + c0 + tc];
        tile[tr + i * 16][tc + 0] = v.x;
        tile[tr + i * 16][tc + 1] = v.y;
        tile[tr + i * 16][tc + 2] = v.z;
        tile[tr + i * 16][tc + 3] = v.w;
    }
    __syncthreads();
#pragma unroll
    for (int i = 0; i < 4; ++i) {
        const int n = tr + i * 16;
        ushort4 o;
        o.x = f2bf(tile[tc + 0][n]);
        o.y = f2bf(tile[tc + 1][n]);
        o.z = f2bf(tile[tc + 2][n]);
        o.w = f2bf(tile[tc + 3][n]);
        *(ushort4*)&dst[(size_t)(c0 + n) * R + r0 + tc] = o;
    }
}

// elementwise fp32 -> bf16
__global__ __launch_bounds__(256) void conv_k(
    const float* __restrict__ src, unsigned short* __restrict__ dst)
{
    const int i = (blockIdx.x * 256 + threadIdx.x) * 4;
    float4 v = *(const float4*)&src[i];
    ushort4 o = {f2bf(v.x), f2bf(v.y), f2bf(v.z), f2bf(v.w)};
    *(ushort4*)&dst[i] = o;
}

// ---------------------------------------------------------------------------
// LayerNorm over H=512, bf16 output.
// ---------------------------------------------------------------------------
__global__ __launch_bounds__(256) void ln_k(
    const float* __restrict__ x, const float* __restrict__ g,
    const float* __restrict__ b, unsigned short* __restrict__ out)
{
    const int row = blockIdx.x;
    const int tid = threadIdx.x;
    const float* xr = x + (size_t)row * H_;

    float v0 = xr[tid];
    float v1 = xr[tid + 256];

    float s = v0 + v1;
#pragma unroll
    for (int off = 32; off; off >>= 1) s += __shfl_xor(s, off);

    __shared__ float red[4];
    const int wave = tid >> 6;
    if ((tid & 63) == 0) red[wave] = s;
    __syncthreads();
    const float mean = (red[0] + red[1] + red[2] + red[3]) * (1.0f / (float)H_);

    const float d0 = v0 - mean, d1 = v1 - mean;
    float q = d0 * d0 + d1 * d1;
#pragma unroll
    for (int off = 32; off; off >>= 1) q += __shfl_xor(q, off);
    __syncthreads();
    if ((tid & 63) == 0) red[wave] = q;
    __syncthreads();
    const float var = (red[0] + red[1] + red[2] + red[3]) * (1.0f / (float)H_);
    const float rstd = rsqrtf(var + 1e-5f);

    out[(size_t)row * H_ + tid]       = f2bf(d0 * rstd * g[tid] + b[tid]);
    out[(size_t)row * H_ + tid + 256] = f2bf(d1 * rstd * g[tid + 256] + b[tid + 256]);
}

// ---------------------------------------------------------------------------
// MFMA banded attention. One block per (b, h, 64-query tile); 4 waves.
// Inputs: q,k,v bf16 [B*T,512] (q,k rotated; q pre-scaled by 0.125).
// V transposed into LDS during staging. S via mfma; softmax in registers;
// P -> LDS bf16; PV via mfma; output vector-stored through Pb.
// ---------------------------------------------------------------------------
#define AWIN 192
#define AKS 72    // ushort stride Qs/Ks
#define AVS 200   // ushort stride Vt/Pb

__global__ __launch_bounds__(256) void attn_k(
    const unsigned short* __restrict__ q, const unsigned short* __restrict__ k,
    const unsigned short* __restrict__ v, const int* __restrict__ smask,
    unsigned short* __restrict__ o)
{
    __shared__ unsigned short Qs[64 * AKS];
    __shared__ unsigned short Ks[AWIN * AKS];
    __shared__ unsigned short Vt[64 * AVS];
    __shared__ unsigned short Pb[64 * AVS];

    const int blk = blockIdx.x;
    const int qt = blk & 15;
    const int h  = (blk >> 4) & 7;
    const int b  = blk >> 7;
    const int tid  = threadIdx.x;
    const int lane = tid & 63;
    const int w    = tid >> 6;
    const int l16  = lane & 15;
    const int g16  = lane >> 4;

    const int qlo = qt * 64;
    const int klo = (qlo >= CB_) ? (qlo - CB_) : 0;

    // ---- stage ----
    {
        const unsigned short* gq = q + ((size_t)(b * 1024 + qlo)) * 512 + h * 64;
        for (int c = tid; c < 64 * 16; c += 256) {
            const int row = c >> 4, c4 = (c & 15) * 4;
            *(ushort4*)&Qs[row * AKS + c4] = *(const ushort4*)&gq[(size_t)row * 512 + c4];
        }
        const unsigned short* gk = k + ((size_t)(b * 1024 + klo)) * 512 + h * 64;
        for (int c = tid; c < AWIN * 16; c += 256) {
            const int row = c >> 4, c4 = (c & 15) * 4;
            *(ushort4*)&Ks[row * AKS + c4] = *(const ushort4*)&gk[(size_t)row * 512 + c4];
        }
        const unsigned short* gv = v + ((size_t)(b * 1024 + klo)) * 512 + h * 64;
        for (int c = tid; c < AWIN * 16; c += 256) {
            const int row = c >> 4, c4 = (c & 15) * 4;
            ushort4 vv = *(const ushort4*)&gv[(size_t)row * 512 + c4];
            Vt[(c4 + 0) * AVS + row] = vv.x;
            Vt[(c4 + 1) * AVS + row] = vv.y;
            Vt[(c4 + 2) * AVS + row] = vv.z;
            Vt[(c4 + 3) * AVS + row] = vv.w;
        }
    }
    __syncthreads();

    // ---- S = Q @ K^T ----
    f32x4 accs[12];
    {
        const bf16x8 a0 = *(const bf16x8*)&Qs[(w * 16 + l16) * AKS + g16 * 8];
        const bf16x8 a1 = *(const bf16x8*)&Qs[(w * 16 + l16) * AKS + 32 + g16 * 8];
#pragma unroll
        for (int t = 0; t < 12; ++t) {
            const bf16x8 b0 = *(const bf16x8*)&Ks[(t * 16 + l16) * AKS + g16 * 8];
            const bf16x8 b1 = *(const bf16x8*)&Ks[(t * 16 + l16) * AKS + 32 + g16 * 8];
            f32x4 c = {};
            c = __builtin_amdgcn_mfma_f32_16x16x32_bf16(a0, b0, c, 0, 0, 0);
            c = __builtin_amdgcn_mfma_f32_16x16x32_bf16(a1, b1, c, 0, 0, 0);
            accs[t] = c;
        }
    }

    // ---- softmax in registers ----
    bool mk[12];
    int  jj[12];
#pragma unroll
    for (int t = 0; t < 12; ++t) {
        jj[t] = klo + t * 16 + l16;
        mk[t] = smask[b * 1024 + jj[t]] > 0;
    }

    float rs[4];
#pragma unroll
    for (int r = 0; r < 4; ++r) {
        const int i = qlo + 16 * w + g16 * 4 + r;
        float mx = -1e30f;
#pragma unroll
        for (int t = 0; t < 12; ++t) {
            const bool val = mk[t] && (jj[t] >= i - CB_) && (jj[t] <= i);
            mx = fmaxf(mx, val ? accs[t][r] : -1e30f);
        }
        mx = fmaxf(mx, __shfl_xor(mx, 1));
        mx = fmaxf(mx, __shfl_xor(mx, 2));
        mx = fmaxf(mx, __shfl_xor(mx, 4));
        mx = fmaxf(mx, __shfl_xor(mx, 8));
        float sum = 0.0f;
#pragma unroll
        for (int t = 0; t < 12; ++t) {
            const bool val = mk[t] && (jj[t] >= i - CB_) && (jj[t] <= i);
            const float p = val ? __expf(accs[t][r] - mx) : 0.0f;
            accs[t][r] = p;
            sum += p;
        }
        sum += __shfl_xor(sum, 1);
        sum += __shfl_xor(sum, 2);
        sum += __shfl_xor(sum, 4);
        sum += __shfl_xor(sum, 8);
        rs[r] = 1.0f / sum;
    }

    // ---- P -> LDS ----
#pragma unroll
    for (int t = 0; t < 12; ++t)
#pragma unroll
        for (int r = 0; r < 4; ++r)
            Pb[(16 * w + g16 * 4 + r) * AVS + t * 16 + l16] = f2bf(accs[t][r]);

    // ---- O = P @ V ----
    f32x4 acco[4];
#pragma unroll
    for (int nt = 0; nt < 4; ++nt) {
        f32x4 c = {};
#pragma unroll
        for (int ks = 0; ks < 6; ++ks) {
            const bf16x8 a = *(const bf16x8*)&Pb[(16 * w + l16) * AVS + ks * 32 + g16 * 8];
            const bf16x8 bb = *(const bf16x8*)&Vt[(nt * 16 + l16) * AVS + ks * 32 + g16 * 8];
            c = __builtin_amdgcn_mfma_f32_16x16x32_bf16(a, bb, c, 0, 0, 0);
        }
        acco[nt] = c;
    }

    // ---- stage O into Pb, vector store ----
    __syncthreads();
#pragma unroll
    for (int nt = 0; nt < 4; ++nt)
#pragma unroll
        for (int r = 0; r < 4; ++r)
            Pb[(16 * w + g16 * 4 + r) * AVS + nt * 16 + l16] = f2bf(acco[nt][r] * rs[r]);

    const int row16 = lane >> 2, cg = lane & 3;
    const int grow = b * 1024 + qlo + 16 * w + row16;
#pragma unroll
    for (int s = 0; s < 4; ++s) {
        ushort4 t4 = *(const ushort4*)&Pb[(16 * w + row16) * AVS + s * 16 + cg * 4];
        *(ushort4*)&o[(size_t)grow * 512 + h * 64 + s * 16 + cg * 4] = t4;
    }
}

// ---------------------------------------------------------------------------
extern "C" void kernel_launch(void* const* d_in, const int* in_sizes, int n_in,
                              void* d_out, int out_size, void* d_ws, size_t ws_size,
                              hipStream_t stream)
{
    const float* spikes  = (const float*)d_in[0];
    const int*   smask   = (const int*)d_in[1];
    const int*   ts      = (const int*)d_in[2];
    const float* embed_w = (const float*)d_in[3];
    const float* embed_b = (const float*)d_in[4];
    const float* proj_w  = (const float*)d_in[5];
    const float* proj_b  = (const float*)d_in[6];
    const float* ln1_g   = (const float*)d_in[7];
    const float* ln1_b   = (const float*)d_in[8];
    const float* Wq      = (const float*)d_in[9];
    const float* bq      = (const float*)d_in[10];
    const float* Wk      = (const float*)d_in[11];
    const float* bk      = (const float*)d_in[12];
    const float* Wv      = (const float*)d_in[13];
    const float* bv      = (const float*)d_in[14];
    const float* Wo      = (const float*)d_in[15];
    const float* bo      = (const float*)d_in[16];
    const float* ln2_g   = (const float*)d_in[17];
    const float* ln2_b   = (const float*)d_in[18];
    const float* up_w    = (const float*)d_in[19];
    const float* up_b    = (const float*)d_in[20];
    const float* down_w  = (const float*)d_in[21];
    const float* down_b  = (const float*)d_in[22];

    const int M = B_ * T_;  // 4096

    char* p = (char*)d_ws;
    float* x = (float*)p;                       p += (size_t)M * H_ * 4;
    unsigned short* qb  = (unsigned short*)p;   p += (size_t)M * H_ * 2;
    unsigned short* kb  = (unsigned short*)p;   p += (size_t)M * H_ * 2;
    unsigned short* vb  = (unsigned short*)p;   p += (size_t)M * H_ * 2;
    unsigned short* hbf = (unsigned short*)p;   p += (size_t)M * H_ * 2;
    unsigned short* obf = (unsigned short*)p;   p += (size_t)M * H_ * 2;
    unsigned short* ibf = (unsigned short*)p;   p += (size_t)M * INTER_ * 2;
    unsigned short* tbf = (unsigned short*)p;   p += (size_t)M * D_ * 2;
    unsigned short* spbf  = (unsigned short*)p; p += (size_t)M * C_ * 2;
    unsigned short* embT  = (unsigned short*)p; p += (size_t)D_ * C_ * 2;
    unsigned short* projT = (unsigned short*)p; p += (size_t)H_ * D_ * 2;
    unsigned short* qkvT  = (unsigned short*)p; p += (size_t)L_ * 3 * H_ * H_ * 2;
    unsigned short* woT   = (unsigned short*)p; p += (size_t)L_ * H_ * H_ * 2;
    unsigned short* upT   = (unsigned short*)p; p += (size_t)L_ * INTER_ * H_ * 2;
    unsigned short* downT = (unsigned short*)p; p += (size_t)L_ * H_ * INTER_ * 2;

    // ---- prologue ----
    conv_k<<<(M * C_) / 1024, 256, 0, stream>>>(spikes, spbf);
    tconv_k<<<dim3(D_ / 64, C_ / 64, 1), 256, 0, stream>>>(embed_w, embT, C_, D_, 0, 0);
    tconv_k<<<dim3(H_ / 64, D_ / 64, 1), 256, 0, stream>>>(proj_w, projT, D_, H_, 0, 0);
    tconv_k<<<dim3(H_ / 64, H_ / 64, L_), 256, 0, stream>>>(
        Wq, qkvT,               H_, H_, (long)H_ * H_, (long)3 * H_ * H_);
    tconv_k<<<dim3(H_ / 64, H_ / 64, L_), 256, 0, stream>>>(
        Wk, qkvT + H_ * H_,     H_, H_, (long)H_ * H_, (long)3 * H_ * H_);
    tconv_k<<<dim3(H_ / 64, H_ / 64, L_), 256, 0, stream>>>(
        Wv, qkvT + 2 * H_ * H_, H_, H_, (long)H_ * H_, (long)3 * H_ * H_);
    tconv_k<<<dim3(H_ / 64, H_ / 64, L_), 256, 0, stream>>>(
        Wo, woT, H_, H_, (long)H_ * H_, (long)H_ * H_);
    tconv_k<<<dim3(INTER_ / 64, H_ / 64, L_), 256, 0, stream>>>(
        up_w, upT, H_, INTER_, (long)H_ * INTER_, (long)INTER_ * H_);
    tconv_k<<<dim3(H_ / 64, INTER_ / 64, L_), 256, 0, stream>>>(
        down_w, downT, INTER_, H_, (long)INTER_ * H_, (long)H_ * INTER_);

    // ---- embedding ----
    mm_k<1, 0, 1, 0><<<dim3(D_ / 128, M / 128), 256, 0, stream>>>(
        spbf, embT, embed_b, nullptr, nullptr, nullptr,
        tbf, nullptr, nullptr, M, D_, C_);
    mm_k<0, 0, 0, 0><<<dim3(H_ / 128, M / 128), 256, 0, stream>>>(
        tbf, projT, proj_b, nullptr, nullptr, nullptr,
        x, nullptr, nullptr, M, H_, D_);

    for (int l = 0; l < L_; ++l) {
        const unsigned short* qkvT_l = qkvT + (size_t)l * 3 * H_ * H_;
        const unsigned short* woT_l  = woT  + (size_t)l * H_ * H_;
        const unsigned short* upT_l  = upT  + (size_t)l * INTER_ * H_;
        const unsigned short* dnT_l  = downT + (size_t)l * H_ * INTER_;

        ln_k<<<M, 256, 0, stream>>>(x, ln1_g + l * H_, ln1_b + l * H_, hbf);

        // fused QKV + bias (+0.125 q scale) -> qb, kb, vb (bf16 [M,512])
        mm_k<0, 0, 1, 1><<<dim3((3 * H_) / 128, M / 128), 256, 0, stream>>>(
            hbf, qkvT_l, bq + l * H_, bk + l * H_, bv + l * H_, nullptr,
            qb, kb, vb, M, 3 * H_, H_);

        // RoPE in-place on bf16 q,k (native trig)
        ropeb_k<<<(B_ * T_ * NH_ * 32) / 256, 256, 0, stream>>>(qb, kb, ts);

        attn_k<<<B_ * NH_ * (T_ / 64), 256, 0, stream>>>(qb, kb, vb, smask, obf);

        mm_k<0, 1, 0, 0><<<dim3(H_ / 128, M / 128), 256, 0, stream>>>(
            obf, woT_l, bo + l * H_, nullptr, nullptr, x,
            x, nullptr, nullptr, M, H_, H_);

        ln_k<<<M, 256, 0, stream>>>(x, ln2_g + l * H_, ln2_b + l * H_, hbf);

        mm_k<1, 0, 1, 0><<<dim3(INTER_ / 128, M / 128), 256, 0, stream>>>(
            hbf, upT_l, up_b + l * INTER_, nullptr, nullptr, nullptr,
            ibf, nullptr, nullptr, M, INTER_, H_);

        float* dst = (l == L_ - 1) ? (float*)d_out : x;
        mm_k<0, 1, 0, 0><<<dim3(H_ / 128, M / 128), 256, 0, stream>>>(
            ibf, dnT_l, down_b + l * H_, nullptr, nullptr, x,
            dst, nullptr, nullptr, M, H_, INTER_);
    }
}

// Round 8
// 685.534 us; speedup vs baseline: 1.9251x; 1.2388x over previous
//
#include <hip/hip_runtime.h>
#include <math.h>

// Problem dims (fixed)
#define B_ 4
#define T_ 1024
#define C_ 256
#define D_ 256
#define H_ 512
#define NH_ 8
#define HD_ 64
#define INTER_ 2048
#define L_ 4
#define CB_ 128   // context_backward; context_forward = 0

typedef short bf16x8 __attribute__((ext_vector_type(8)));
typedef float f32x4 __attribute__((ext_vector_type(4)));

__device__ __forceinline__ float gelu_exact(float x) {
    return 0.5f * x * (1.0f + erff(x * 0.70710678118654752f));
}

// fp32 -> bf16 round-to-nearest-even
__device__ __forceinline__ unsigned short f2bf(float f) {
    unsigned u = __float_as_uint(f);
    u += 0x7fffu + ((u >> 16) & 1u);
    return (unsigned short)(u >> 16);
}
__device__ __forceinline__ float bf2f(unsigned short h) {
    return __uint_as_float((unsigned)h << 16);
}

// ---------------------------------------------------------------------------
// bf16 MFMA GEMM, 128x128 tile (for large-N GEMMs: QKV N=1536, up N=2048).
// 256 threads (4 waves 2x2), each wave 4x4 of 16x16x32 MFMA, BK=32,
// global_load_lds width-16 staging. bf16 outputs via in-LDS transpose.
// SPLIT=1: QKV; routes q/k/v by 64-col strip; q scaled 0.125; no trig.
// ---------------------------------------------------------------------------
template<int ACT, int RES, int OBF, int SPLIT>
__global__ __launch_bounds__(256) void mm_k(
    const unsigned short* __restrict__ A, const unsigned short* __restrict__ BT,
    const float* __restrict__ b0, const float* __restrict__ b1,
    const float* __restrict__ b2,
    const float* res,
    void* o0, void* o1, void* o2,
    const int M, const int N, const int K)
{
    __shared__ unsigned short As[128 * 32];
    __shared__ unsigned short Bs[128 * 32];

    const int tid  = threadIdx.x;
    const int lane = tid & 63;
    const int w    = tid >> 6;
    const int m0   = blockIdx.y * 128;
    const int n0   = blockIdx.x * 128;
    const int wm   = (w >> 1) * 64;
    const int wn   = (w & 1) * 64;
    const int l16  = lane & 15;
    const int g16  = lane >> 4;
    const int fk   = g16 * 8;

    f32x4 acc[4][4] = {};

    const int c0 = (w << 6) + lane;
    const int c1 = c0 + 256;

    const unsigned short* Abase = A  + (size_t)m0 * K;
    const unsigned short* Bbase = BT + (size_t)n0 * K;

    for (int k0 = 0; k0 < K; k0 += 32) {
        __syncthreads();
        const unsigned short* ga0 = Abase + (size_t)(c0 >> 2) * K + k0 + (c0 & 3) * 8;
        const unsigned short* ga1 = Abase + (size_t)(c1 >> 2) * K + k0 + (c1 & 3) * 8;
        __builtin_amdgcn_global_load_lds(
            (const __attribute__((address_space(1))) unsigned*)ga0,
            (__attribute__((address_space(3))) unsigned*)(As + (size_t)(w << 6) * 8), 16, 0, 0);
        __builtin_amdgcn_global_load_lds(
            (const __attribute__((address_space(1))) unsigned*)ga1,
            (__attribute__((address_space(3))) unsigned*)(As + (size_t)(256 + (w << 6)) * 8), 16, 0, 0);
        const unsigned short* gb0 = Bbase + (size_t)(c0 >> 2) * K + k0 + (c0 & 3) * 8;
        const unsigned short* gb1 = Bbase + (size_t)(c1 >> 2) * K + k0 + (c1 & 3) * 8;
        __builtin_amdgcn_global_load_lds(
            (const __attribute__((address_space(1))) unsigned*)gb0,
            (__attribute__((address_space(3))) unsigned*)(Bs + (size_t)(w << 6) * 8), 16, 0, 0);
        __builtin_amdgcn_global_load_lds(
            (const __attribute__((address_space(1))) unsigned*)gb1,
            (__attribute__((address_space(3))) unsigned*)(Bs + (size_t)(256 + (w << 6)) * 8), 16, 0, 0);
        __syncthreads();

        bf16x8 a[4], b[4];
#pragma unroll
        for (int t = 0; t < 4; ++t)
            a[t] = *(const bf16x8*)&As[(wm + t * 16 + l16) * 32 + fk];
#pragma unroll
        for (int t = 0; t < 4; ++t)
            b[t] = *(const bf16x8*)&Bs[(wn + t * 16 + l16) * 32 + fk];
#pragma unroll
        for (int i = 0; i < 4; ++i)
#pragma unroll
            for (int j = 0; j < 4; ++j)
                acc[i][j] = __builtin_amdgcn_mfma_f32_16x16x32_bf16(a[i], b[j], acc[i][j], 0, 0, 0);
    }

    if (OBF || SPLIT) {
        __syncthreads();
        unsigned short* Eb = (w < 2) ? (As + w * 1152) : (Bs + (w - 2) * 1152);
        const int row16 = lane >> 2;
        const int cg    = lane & 3;

        const int gnb   = n0 + wn;
        const int which = SPLIT ? (gnb >> 9) : 0;
        const int lnb   = SPLIT ? (gnb & 511) : gnb;
        const int ldo   = SPLIT ? 512 : N;
        unsigned short* oo = SPLIT
            ? ((which == 0) ? (unsigned short*)o0 : (which == 1) ? (unsigned short*)o1 : (unsigned short*)o2)
            : (unsigned short*)o0;
        const float* bb = SPLIT ? ((which == 0) ? b0 : (which == 1) ? b1 : b2) : b0;
        const float scale = (SPLIT && which == 0) ? 0.125f : 1.0f;

#pragma unroll
        for (int i = 0; i < 4; ++i) {
#pragma unroll
            for (int j = 0; j < 4; ++j) {
                const float bv = bb[lnb + j * 16 + l16];
#pragma unroll
                for (int r = 0; r < 4; ++r) {
                    float cv = acc[i][j][r] + bv;
                    if (ACT) cv = gelu_exact(cv);
                    if (SPLIT) cv *= scale;
                    Eb[(g16 * 4 + r) * 72 + j * 16 + l16] = f2bf(cv);
                }
            }
            const int grow0 = m0 + wm + i * 16 + row16;
#pragma unroll
            for (int s = 0; s < 4; ++s) {
                ushort4 t4 = *(const ushort4*)&Eb[row16 * 72 + s * 16 + cg * 4];
                *(ushort4*)&oo[(size_t)grow0 * ldo + lnb + s * 16 + cg * 4] = t4;
            }
        }
        return;
    }

    // fp32 output epilogue
#pragma unroll
    for (int i = 0; i < 4; ++i) {
        const int gmb = m0 + wm + i * 16 + g16 * 4;
#pragma unroll
        for (int j = 0; j < 4; ++j) {
            const int gn = n0 + wn + j * 16 + l16;
            const float bv = b0[gn];
#pragma unroll
            for (int r = 0; r < 4; ++r) {
                float cv = acc[i][j][r] + bv;
                if (ACT) cv = gelu_exact(cv);
                if (RES) cv += res[(size_t)(gmb + r) * 512 + gn];
                ((float*)o0)[(size_t)(gmb + r) * N + gn] = cv;
            }
        }
    }
}

// ---------------------------------------------------------------------------
// bf16 MFMA GEMM, 64x64 tile — for small-N GEMMs (N<=512: down-proj, Wo,
// embed). 4x more blocks than the 128-tile => 2+ blocks/CU at N=512
// (128-tile gave 128 blocks on 256 CUs: half-idle GPU, Occupancy 5%, R7).
// 256 threads, 4 waves 2x2, each wave 32x32 via 2x2 MFMA. BK=32; one
// global_load_lds issue per buffer per k-step.
// ---------------------------------------------------------------------------
template<int ACT, int RES, int OBF>
__global__ __launch_bounds__(256) void mm64_k(
    const unsigned short* __restrict__ A, const unsigned short* __restrict__ BT,
    const float* __restrict__ bias, const float* res, void* out,
    const int M, const int N, const int K)
{
    __shared__ unsigned short As[64 * 32];
    __shared__ unsigned short Bs[64 * 32];

    const int tid  = threadIdx.x;
    const int lane = tid & 63;
    const int w    = tid >> 6;
    const int m0   = blockIdx.y * 64;
    const int n0   = blockIdx.x * 64;
    const int wm   = (w >> 1) * 32;
    const int wn   = (w & 1) * 32;
    const int l16  = lane & 15;
    const int g16  = lane >> 4;
    const int fk   = g16 * 8;

    f32x4 acc[2][2] = {};

    const unsigned short* Abase = A  + (size_t)m0 * K;
    const unsigned short* Bbase = BT + (size_t)n0 * K;
    const int crow = tid >> 2;          // 0..63
    const int ck   = (tid & 3) * 8;     // 0,8,16,24

    for (int k0 = 0; k0 < K; k0 += 32) {
        __syncthreads();
        const unsigned short* ga = Abase + (size_t)crow * K + k0 + ck;
        __builtin_amdgcn_global_load_lds(
            (const __attribute__((address_space(1))) unsigned*)ga,
            (__attribute__((address_space(3))) unsigned*)(As + (size_t)(w << 6) * 8), 16, 0, 0);
        const unsigned short* gb = Bbase + (size_t)crow * K + k0 + ck;
        __builtin_amdgcn_global_load_lds(
            (const __attribute__((address_space(1))) unsigned*)gb,
            (__attribute__((address_space(3))) unsigned*)(Bs + (size_t)(w << 6) * 8), 16, 0, 0);
        __syncthreads();

        bf16x8 a[2], b[2];
#pragma unroll
        for (int t = 0; t < 2; ++t)
            a[t] = *(const bf16x8*)&As[(wm + t * 16 + l16) * 32 + fk];
#pragma unroll
        for (int t = 0; t < 2; ++t)
            b[t] = *(const bf16x8*)&Bs[(wn + t * 16 + l16) * 32 + fk];
#pragma unroll
        for (int i = 0; i < 2; ++i)
#pragma unroll
            for (int j = 0; j < 2; ++j)
                acc[i][j] = __builtin_amdgcn_mfma_f32_16x16x32_bf16(a[i], b[j], acc[i][j], 0, 0, 0);
    }

    if (OBF) {
        // bf16 out: per-wave LDS transpose (16x40-stride tile), ushort4 stores
        __syncthreads();
        unsigned short* Eb = ((w < 2) ? As : Bs) + (w & 1) * 1024;
        const int row16 = lane >> 2;
        const int cg    = lane & 3;
#pragma unroll
        for (int i = 0; i < 2; ++i) {
#pragma unroll
            for (int j = 0; j < 2; ++j) {
                const float bv = bias[n0 + wn + j * 16 + l16];
#pragma unroll
                for (int r = 0; r < 4; ++r) {
                    float cv = acc[i][j][r] + bv;
                    if (ACT) cv = gelu_exact(cv);
                    Eb[(g16 * 4 + r) * 40 + j * 16 + l16] = f2bf(cv);
                }
            }
            const int grow0 = m0 + wm + i * 16 + row16;
#pragma unroll
            for (int s = 0; s < 2; ++s) {
                ushort4 t4 = *(const ushort4*)&Eb[row16 * 40 + s * 16 + cg * 4];
                *(ushort4*)&((unsigned short*)out)[(size_t)grow0 * N + n0 + wn + s * 16 + cg * 4] = t4;
            }
        }
        return;
    }

    // fp32 out epilogue
#pragma unroll
    for (int i = 0; i < 2; ++i) {
        const int gmb = m0 + wm + i * 16 + g16 * 4;
#pragma unroll
        for (int j = 0; j < 2; ++j) {
            const int gn = n0 + wn + j * 16 + l16;
            const float bv = bias[gn];
#pragma unroll
            for (int r = 0; r < 4; ++r) {
                float cv = acc[i][j][r] + bv;
                if (ACT) cv = gelu_exact(cv);
                if (RES) cv += res[(size_t)(gmb + r) * 512 + gn];
                ((float*)out)[(size_t)(gmb + r) * N + gn] = cv;
            }
        }
    }
}

// ---------------------------------------------------------------------------
// RoPE in-place on bf16 q,k [B*T,512]. Native trig (arg <= ~1023 rad).
// ---------------------------------------------------------------------------
__global__ __launch_bounds__(256) void ropeb_k(
    unsigned short* __restrict__ q, unsigned short* __restrict__ k,
    const int* __restrict__ ts)
{
    const int idx = blockIdx.x * 256 + threadIdx.x;
    const int d  = idx & 31;
    const int nh = (idx >> 5) & (NH_ - 1);
    const int t  = (idx >> 8) & (T_ - 1);
    const int b  = idx >> 18;

    const float freq = __expf(-0.2878231366242558f * (float)d);
    const float ang = (float)ts[b * T_ + t] * freq;
    const float cc = __cosf(ang);
    const float ss = __sinf(ang);

    const size_t base = ((size_t)(b * T_ + t)) * 512 + nh * 64 + d;
    const float q1 = bf2f(q[base]), q2 = bf2f(q[base + 32]);
    q[base]      = f2bf(q1 * cc - q2 * ss);
    q[base + 32] = f2bf(q2 * cc + q1 * ss);
    const float k1 = bf2f(k[base]), k2 = bf2f(k[base + 32]);
    k[base]      = f2bf(k1 * cc - k2 * ss);
    k[base + 32] = f2bf(k2 * cc + k1 * ss);
}

// ---------------------------------------------------------------------------
// Transpose + fp32->bf16: src [R,Cc] fp32 -> dst [Cc,R] bf16. 64x64 tiles.
// ---------------------------------------------------------------------------
__global__ __launch_bounds__(256) void tconv_k(
    const float* __restrict__ src, unsigned short* __restrict__ dst,
    int R, int Cc, long slay, long dlay)
{
    __shared__ float tile[64][65];
    const int t = threadIdx.x;
    src += (size_t)blockIdx.z * slay;
    dst += (size_t)blockIdx.z * dlay;
    const int r0 = blockIdx.y * 64, c0 = blockIdx.x * 64;
    const int tr = t >> 4, tc = (t & 15) * 4;
#pragma unroll
    for (int i = 0; i < 4; ++i) {
        float4 v = *(const float4*)&src[(size_t)(r0 + tr + i * 16) * Cc + c0 + tc];
        tile[tr + i * 16][tc + 0] = v.x;
        tile[tr + i * 16][tc + 1] = v.y;
        tile[tr + i * 16][tc + 2] = v.z;
        tile[tr + i * 16][tc + 3] = v.w;
    }
    __syncthreads();
#pragma unroll
    for (int i = 0; i < 4; ++i) {
        const int n = tr + i * 16;
        ushort4 o;
        o.x = f2bf(tile[tc + 0][n]);
        o.y = f2bf(tile[tc + 1][n]);
        o.z = f2bf(tile[tc + 2][n]);
        o.w = f2bf(tile[tc + 3][n]);
        *(ushort4*)&dst[(size_t)(c0 + n) * R + r0 + tc] = o;
    }
}

// elementwise fp32 -> bf16
__global__ __launch_bounds__(256) void conv_k(
    const float* __restrict__ src, unsigned short* __restrict__ dst)
{
    const int i = (blockIdx.x * 256 + threadIdx.x) * 4;
    float4 v = *(const float4*)&src[i];
    ushort4 o = {f2bf(v.x), f2bf(v.y), f2bf(v.z), f2bf(v.w)};
    *(ushort4*)&dst[i] = o;
}

// ---------------------------------------------------------------------------
// LayerNorm over H=512, bf16 output.
// ---------------------------------------------------------------------------
__global__ __launch_bounds__(256) void ln_k(
    const float* __restrict__ x, const float* __restrict__ g,
    const float* __restrict__ b, unsigned short* __restrict__ out)
{
    const int row = blockIdx.x;
    const int tid = threadIdx.x;
    const float* xr = x + (size_t)row * H_;

    float v0 = xr[tid];
    float v1 = xr[tid + 256];

    float s = v0 + v1;
#pragma unroll
    for (int off = 32; off; off >>= 1) s += __shfl_xor(s, off);

    __shared__ float red[4];
    const int wave = tid >> 6;
    if ((tid & 63) == 0) red[wave] = s;
    __syncthreads();
    const float mean = (red[0] + red[1] + red[2] + red[3]) * (1.0f / (float)H_);

    const float d0 = v0 - mean, d1 = v1 - mean;
    float q = d0 * d0 + d1 * d1;
#pragma unroll
    for (int off = 32; off; off >>= 1) q += __shfl_xor(q, off);
    __syncthreads();
    if ((tid & 63) == 0) red[wave] = q;
    __syncthreads();
    const float var = (red[0] + red[1] + red[2] + red[3]) * (1.0f / (float)H_);
    const float rstd = rsqrtf(var + 1e-5f);

    out[(size_t)row * H_ + tid]       = f2bf(d0 * rstd * g[tid] + b[tid]);
    out[(size_t)row * H_ + tid + 256] = f2bf(d1 * rstd * g[tid + 256] + b[tid + 256]);
}

// ---------------------------------------------------------------------------
// MFMA banded attention (unchanged from R7 pass).
// ---------------------------------------------------------------------------
#define AWIN 192
#define AKS 72
#define AVS 200

__global__ __launch_bounds__(256) void attn_k(
    const unsigned short* __restrict__ q, const unsigned short* __restrict__ k,
    const unsigned short* __restrict__ v, const int* __restrict__ smask,
    unsigned short* __restrict__ o)
{
    __shared__ unsigned short Qs[64 * AKS];
    __shared__ unsigned short Ks[AWIN * AKS];
    __shared__ unsigned short Vt[64 * AVS];
    __shared__ unsigned short Pb[64 * AVS];

    const int blk = blockIdx.x;
    const int qt = blk & 15;
    const int h  = (blk >> 4) & 7;
    const int b  = blk >> 7;
    const int tid  = threadIdx.x;
    const int lane = tid & 63;
    const int w    = tid >> 6;
    const int l16  = lane & 15;
    const int g16  = lane >> 4;

    const int qlo = qt * 64;
    const int klo = (qlo >= CB_) ? (qlo - CB_) : 0;

    {
        const unsigned short* gq = q + ((size_t)(b * 1024 + qlo)) * 512 + h * 64;
        for (int c = tid; c < 64 * 16; c += 256) {
            const int row = c >> 4, c4 = (c & 15) * 4;
            *(ushort4*)&Qs[row * AKS + c4] = *(const ushort4*)&gq[(size_t)row * 512 + c4];
        }
        const unsigned short* gk = k + ((size_t)(b * 1024 + klo)) * 512 + h * 64;
        for (int c = tid; c < AWIN * 16; c += 256) {
            const int row = c >> 4, c4 = (c & 15) * 4;
            *(ushort4*)&Ks[row * AKS + c4] = *(const ushort4*)&gk[(size_t)row * 512 + c4];
        }
        const unsigned short* gv = v + ((size_t)(b * 1024 + klo)) * 512 + h * 64;
        for (int c = tid; c < AWIN * 16; c += 256) {
            const int row = c >> 4, c4 = (c & 15) * 4;
            ushort4 vv = *(const ushort4*)&gv[(size_t)row * 512 + c4];
            Vt[(c4 + 0) * AVS + row] = vv.x;
            Vt[(c4 + 1) * AVS + row] = vv.y;
            Vt[(c4 + 2) * AVS + row] = vv.z;
            Vt[(c4 + 3) * AVS + row] = vv.w;
        }
    }
    __syncthreads();

    f32x4 accs[12];
    {
        const bf16x8 a0 = *(const bf16x8*)&Qs[(w * 16 + l16) * AKS + g16 * 8];
        const bf16x8 a1 = *(const bf16x8*)&Qs[(w * 16 + l16) * AKS + 32 + g16 * 8];
#pragma unroll
        for (int t = 0; t < 12; ++t) {
            const bf16x8 b0 = *(const bf16x8*)&Ks[(t * 16 + l16) * AKS + g16 * 8];
            const bf16x8 b1 = *(const bf16x8*)&Ks[(t * 16 + l16) * AKS + 32 + g16 * 8];
            f32x4 c = {};
            c = __builtin_amdgcn_mfma_f32_16x16x32_bf16(a0, b0, c, 0, 0, 0);
            c = __builtin_amdgcn_mfma_f32_16x16x32_bf16(a1, b1, c, 0, 0, 0);
            accs[t] = c;
        }
    }

    bool mk[12];
    int  jj[12];
#pragma unroll
    for (int t = 0; t < 12; ++t) {
        jj[t] = klo + t * 16 + l16;
        mk[t] = smask[b * 1024 + jj[t]] > 0;
    }

    float rs[4];
#pragma unroll
    for (int r = 0; r < 4; ++r) {
        const int i = qlo + 16 * w + g16 * 4 + r;
        float mx = -1e30f;
#pragma unroll
        for (int t = 0; t < 12; ++t) {
            const bool val = mk[t] && (jj[t] >= i - CB_) && (jj[t] <= i);
            mx = fmaxf(mx, val ? accs[t][r] : -1e30f);
        }
        mx = fmaxf(mx, __shfl_xor(mx, 1));
        mx = fmaxf(mx, __shfl_xor(mx, 2));
        mx = fmaxf(mx, __shfl_xor(mx, 4));
        mx = fmaxf(mx, __shfl_xor(mx, 8));
        float sum = 0.0f;
#pragma unroll
        for (int t = 0; t < 12; ++t) {
            const bool val = mk[t] && (jj[t] >= i - CB_) && (jj[t] <= i);
            const float p = val ? __expf(accs[t][r] - mx) : 0.0f;
            accs[t][r] = p;
            sum += p;
        }
        sum += __shfl_xor(sum, 1);
        sum += __shfl_xor(sum, 2);
        sum += __shfl_xor(sum, 4);
        sum += __shfl_xor(sum, 8);
        rs[r] = 1.0f / sum;
    }

#pragma unroll
    for (int t = 0; t < 12; ++t)
#pragma unroll
        for (int r = 0; r < 4; ++r)
            Pb[(16 * w + g16 * 4 + r) * AVS + t * 16 + l16] = f2bf(accs[t][r]);

    f32x4 acco[4];
#pragma unroll
    for (int nt = 0; nt < 4; ++nt) {
        f32x4 c = {};
#pragma unroll
        for (int ks = 0; ks < 6; ++ks) {
            const bf16x8 a = *(const bf16x8*)&Pb[(16 * w + l16) * AVS + ks * 32 + g16 * 8];
            const bf16x8 bb = *(const bf16x8*)&Vt[(nt * 16 + l16) * AVS + ks * 32 + g16 * 8];
            c = __builtin_amdgcn_mfma_f32_16x16x32_bf16(a, bb, c, 0, 0, 0);
        }
        acco[nt] = c;
    }

    __syncthreads();
#pragma unroll
    for (int nt = 0; nt < 4; ++nt)
#pragma unroll
        for (int r = 0; r < 4; ++r)
            Pb[(16 * w + g16 * 4 + r) * AVS + nt * 16 + l16] = f2bf(acco[nt][r] * rs[r]);

    const int row16 = lane >> 2, cg = lane & 3;
    const int grow = b * 1024 + qlo + 16 * w + row16;
#pragma unroll
    for (int s = 0; s < 4; ++s) {
        ushort4 t4 = *(const ushort4*)&Pb[(16 * w + row16) * AVS + s * 16 + cg * 4];
        *(ushort4*)&o[(size_t)grow * 512 + h * 64 + s * 16 + cg * 4] = t4;
    }
}

// ---------------------------------------------------------------------------
extern "C" void kernel_launch(void* const* d_in, const int* in_sizes, int n_in,
                              void* d_out, int out_size, void* d_ws, size_t ws_size,
                              hipStream_t stream)
{
    const float* spikes  = (const float*)d_in[0];
    const int*   smask   = (const int*)d_in[1];
    const int*   ts      = (const int*)d_in[2];
    const float* embed_w = (const float*)d_in[3];
    const float* embed_b = (const float*)d_in[4];
    const float* proj_w  = (const float*)d_in[5];
    const float* proj_b  = (const float*)d_in[6];
    const float* ln1_g   = (const float*)d_in[7];
    const float* ln1_b   = (const float*)d_in[8];
    const float* Wq      = (const float*)d_in[9];
    const float* bq      = (const float*)d_in[10];
    const float* Wk      = (const float*)d_in[11];
    const float* bk      = (const float*)d_in[12];
    const float* Wv      = (const float*)d_in[13];
    const float* bv      = (const float*)d_in[14];
    const float* Wo      = (const float*)d_in[15];
    const float* bo      = (const float*)d_in[16];
    const float* ln2_g   = (const float*)d_in[17];
    const float* ln2_b   = (const float*)d_in[18];
    const float* up_w    = (const float*)d_in[19];
    const float* up_b    = (const float*)d_in[20];
    const float* down_w  = (const float*)d_in[21];
    const float* down_b  = (const float*)d_in[22];

    const int M = B_ * T_;  // 4096

    char* p = (char*)d_ws;
    float* x = (float*)p;                       p += (size_t)M * H_ * 4;
    unsigned short* qb  = (unsigned short*)p;   p += (size_t)M * H_ * 2;
    unsigned short* kb  = (unsigned short*)p;   p += (size_t)M * H_ * 2;
    unsigned short* vb  = (unsigned short*)p;   p += (size_t)M * H_ * 2;
    unsigned short* hbf = (unsigned short*)p;   p += (size_t)M * H_ * 2;
    unsigned short* obf = (unsigned short*)p;   p += (size_t)M * H_ * 2;
    unsigned short* ibf = (unsigned short*)p;   p += (size_t)M * INTER_ * 2;
    unsigned short* tbf = (unsigned short*)p;   p += (size_t)M * D_ * 2;
    unsigned short* spbf  = (unsigned short*)p; p += (size_t)M * C_ * 2;
    unsigned short* embT  = (unsigned short*)p; p += (size_t)D_ * C_ * 2;
    unsigned short* projT = (unsigned short*)p; p += (size_t)H_ * D_ * 2;
    unsigned short* qkvT  = (unsigned short*)p; p += (size_t)L_ * 3 * H_ * H_ * 2;
    unsigned short* woT   = (unsigned short*)p; p += (size_t)L_ * H_ * H_ * 2;
    unsigned short* upT   = (unsigned short*)p; p += (size_t)L_ * INTER_ * H_ * 2;
    unsigned short* downT = (unsigned short*)p; p += (size_t)L_ * H_ * INTER_ * 2;

    // ---- prologue ----
    conv_k<<<(M * C_) / 1024, 256, 0, stream>>>(spikes, spbf);
    tconv_k<<<dim3(D_ / 64, C_ / 64, 1), 256, 0, stream>>>(embed_w, embT, C_, D_, 0, 0);
    tconv_k<<<dim3(H_ / 64, D_ / 64, 1), 256, 0, stream>>>(proj_w, projT, D_, H_, 0, 0);
    tconv_k<<<dim3(H_ / 64, H_ / 64, L_), 256, 0, stream>>>(
        Wq, qkvT,               H_, H_, (long)H_ * H_, (long)3 * H_ * H_);
    tconv_k<<<dim3(H_ / 64, H_ / 64, L_), 256, 0, stream>>>(
        Wk, qkvT + H_ * H_,     H_, H_, (long)H_ * H_, (long)3 * H_ * H_);
    tconv_k<<<dim3(H_ / 64, H_ / 64, L_), 256, 0, stream>>>(
        Wv, qkvT + 2 * H_ * H_, H_, H_, (long)H_ * H_, (long)3 * H_ * H_);
    tconv_k<<<dim3(H_ / 64, H_ / 64, L_), 256, 0, stream>>>(
        Wo, woT, H_, H_, (long)H_ * H_, (long)H_ * H_);
    tconv_k<<<dim3(INTER_ / 64, H_ / 64, L_), 256, 0, stream>>>(
        up_w, upT, H_, INTER_, (long)H_ * INTER_, (long)INTER_ * H_);
    tconv_k<<<dim3(H_ / 64, INTER_ / 64, L_), 256, 0, stream>>>(
        down_w, downT, INTER_, H_, (long)INTER_ * H_, (long)H_ * INTER_);

    // ---- embedding (small-N: 64-tile) ----
    mm64_k<1, 0, 1><<<dim3(D_ / 64, M / 64), 256, 0, stream>>>(
        spbf, embT, embed_b, nullptr, tbf, M, D_, C_);
    mm64_k<0, 0, 0><<<dim3(H_ / 64, M / 64), 256, 0, stream>>>(
        tbf, projT, proj_b, nullptr, x, M, H_, D_);

    for (int l = 0; l < L_; ++l) {
        const unsigned short* qkvT_l = qkvT + (size_t)l * 3 * H_ * H_;
        const unsigned short* woT_l  = woT  + (size_t)l * H_ * H_;
        const unsigned short* upT_l  = upT  + (size_t)l * INTER_ * H_;
        const unsigned short* dnT_l  = downT + (size_t)l * H_ * INTER_;

        ln_k<<<M, 256, 0, stream>>>(x, ln1_g + l * H_, ln1_b + l * H_, hbf);

        // fused QKV + bias (+0.125 q scale) -> qb, kb, vb (bf16 [M,512])
        mm_k<0, 0, 1, 1><<<dim3((3 * H_) / 128, M / 128), 256, 0, stream>>>(
            hbf, qkvT_l, bq + l * H_, bk + l * H_, bv + l * H_, nullptr,
            qb, kb, vb, M, 3 * H_, H_);

        ropeb_k<<<(B_ * T_ * NH_ * 32) / 256, 256, 0, stream>>>(qb, kb, ts);

        attn_k<<<B_ * NH_ * (T_ / 64), 256, 0, stream>>>(qb, kb, vb, smask, obf);

        // x = x + obuf @ Wo + bo  (small-N: 64-tile, 512 blocks)
        mm64_k<0, 1, 0><<<dim3(H_ / 64, M / 64), 256, 0, stream>>>(
            obf, woT_l, bo + l * H_, x, x, M, H_, H_);

        ln_k<<<M, 256, 0, stream>>>(x, ln2_g + l * H_, ln2_b + l * H_, hbf);

        mm_k<1, 0, 1, 0><<<dim3(INTER_ / 128, M / 128), 256, 0, stream>>>(
            hbf, upT_l, up_b + l * INTER_, nullptr, nullptr, nullptr,
            ibf, nullptr, nullptr, M, INTER_, H_);

        // x = x + inter @ down_w + b  (small-N: 64-tile, 512 blocks)
        float* dst = (l == L_ - 1) ? (float*)d_out : x;
        mm64_k<0, 1, 0><<<dim3(H_ / 64, M / 64), 256, 0, stream>>>(
            ibf, dnT_l, down_b + l * H_, x, dst, M, H_, INTER_);
    }
}

// Round 9
// 628.804 us; speedup vs baseline: 2.0988x; 1.0902x over previous
//
#include <hip/hip_runtime.h>
#include <math.h>

// Problem dims (fixed)
#define B_ 4
#define T_ 1024
#define C_ 256
#define D_ 256
#define H_ 512
#define NH_ 8
#define HD_ 64
#define INTER_ 2048
#define L_ 4
#define CB_ 128   // context_backward; context_forward = 0

typedef short bf16x8 __attribute__((ext_vector_type(8)));
typedef float f32x4 __attribute__((ext_vector_type(4)));

__device__ __forceinline__ float gelu_exact(float x) {
    return 0.5f * x * (1.0f + erff(x * 0.70710678118654752f));
}

// fp32 -> bf16 round-to-nearest-even
__device__ __forceinline__ unsigned short f2bf(float f) {
    unsigned u = __float_as_uint(f);
    u += 0x7fffu + ((u >> 16) & 1u);
    return (unsigned short)(u >> 16);
}
__device__ __forceinline__ float bf2f(unsigned short h) {
    return __uint_as_float((unsigned)h << 16);
}

// ---------------------------------------------------------------------------
// bf16 MFMA GEMM, 64x64 tile — used for ALL GEMMs. Maximizes block count
// (occupancy was the binding constraint for every shape here: R7 showed the
// 128-tile at N=512 left half the GPU idle; R8's 64-tile fixed down/Wo;
// this round up-proj (2048 blocks, 8/CU) and QKV (1536 blocks, 6/CU) move
// over too). 256 threads, 4 waves 2x2, each wave 32x32 via 2x2 MFMA of
// 16x16x32. BK=32; one global_load_lds width-16 issue per buffer per step.
// SPLIT=1: QKV mode, N=1536 (q 0-511, k 512-1023, v 1024-1535): routes
// output/bias by 32-col strip, scales q by 0.125. No trig here (R4/R5:
// libm sincos in epilogue = latency disaster; RoPE is standalone).
// bf16 outputs via per-wave in-LDS transpose -> ushort4 stores (32B runs;
// R4: scalar/scatter bf16 stores caused ~29x HBM write amplification).
// ---------------------------------------------------------------------------
template<int ACT, int RES, int OBF, int SPLIT>
__global__ __launch_bounds__(256) void mm64_k(
    const unsigned short* __restrict__ A, const unsigned short* __restrict__ BT,
    const float* __restrict__ b0, const float* __restrict__ b1,
    const float* __restrict__ b2,
    const float* res,
    void* o0, void* o1, void* o2,
    const int M, const int N, const int K)
{
    __shared__ unsigned short As[64 * 32];
    __shared__ unsigned short Bs[64 * 32];

    const int tid  = threadIdx.x;
    const int lane = tid & 63;
    const int w    = tid >> 6;
    const int m0   = blockIdx.y * 64;
    const int n0   = blockIdx.x * 64;
    const int wm   = (w >> 1) * 32;
    const int wn   = (w & 1) * 32;
    const int l16  = lane & 15;
    const int g16  = lane >> 4;
    const int fk   = g16 * 8;

    f32x4 acc[2][2] = {};

    const unsigned short* Abase = A  + (size_t)m0 * K;
    const unsigned short* Bbase = BT + (size_t)n0 * K;
    const int crow = tid >> 2;          // 0..63
    const int ck   = (tid & 3) * 8;     // 0,8,16,24

    for (int k0 = 0; k0 < K; k0 += 32) {
        __syncthreads();
        const unsigned short* ga = Abase + (size_t)crow * K + k0 + ck;
        __builtin_amdgcn_global_load_lds(
            (const __attribute__((address_space(1))) unsigned*)ga,
            (__attribute__((address_space(3))) unsigned*)(As + (size_t)(w << 6) * 8), 16, 0, 0);
        const unsigned short* gb = Bbase + (size_t)crow * K + k0 + ck;
        __builtin_amdgcn_global_load_lds(
            (const __attribute__((address_space(1))) unsigned*)gb,
            (__attribute__((address_space(3))) unsigned*)(Bs + (size_t)(w << 6) * 8), 16, 0, 0);
        __syncthreads();

        bf16x8 a[2], b[2];
#pragma unroll
        for (int t = 0; t < 2; ++t)
            a[t] = *(const bf16x8*)&As[(wm + t * 16 + l16) * 32 + fk];
#pragma unroll
        for (int t = 0; t < 2; ++t)
            b[t] = *(const bf16x8*)&Bs[(wn + t * 16 + l16) * 32 + fk];
#pragma unroll
        for (int i = 0; i < 2; ++i)
#pragma unroll
            for (int j = 0; j < 2; ++j)
                acc[i][j] = __builtin_amdgcn_mfma_f32_16x16x32_bf16(a[i], b[j], acc[i][j], 0, 0, 0);
    }

    if (OBF || SPLIT) {
        __syncthreads();
        unsigned short* Eb = ((w < 2) ? As : Bs) + (w & 1) * 1024;
        const int row16 = lane >> 2;
        const int cg    = lane & 3;

        const int gnb   = n0 + wn;                // 32-col strip base
        const int which = SPLIT ? (gnb >> 9) : 0;
        const int lnb   = SPLIT ? (gnb & 511) : gnb;
        const int ldo   = SPLIT ? 512 : N;
        unsigned short* oo = SPLIT
            ? ((which == 0) ? (unsigned short*)o0 : (which == 1) ? (unsigned short*)o1 : (unsigned short*)o2)
            : (unsigned short*)o0;
        const float* bb = SPLIT ? ((which == 0) ? b0 : (which == 1) ? b1 : b2) : b0;
        const float scale = (SPLIT && which == 0) ? 0.125f : 1.0f;

#pragma unroll
        for (int i = 0; i < 2; ++i) {
#pragma unroll
            for (int j = 0; j < 2; ++j) {
                const float bv = bb[lnb + j * 16 + l16];
#pragma unroll
                for (int r = 0; r < 4; ++r) {
                    float cv = acc[i][j][r] + bv;
                    if (ACT) cv = gelu_exact(cv);
                    if (SPLIT) cv *= scale;
                    Eb[(g16 * 4 + r) * 40 + j * 16 + l16] = f2bf(cv);
                }
            }
            const int grow0 = m0 + wm + i * 16 + row16;
#pragma unroll
            for (int s = 0; s < 2; ++s) {
                ushort4 t4 = *(const ushort4*)&Eb[row16 * 40 + s * 16 + cg * 4];
                *(ushort4*)&oo[(size_t)grow0 * ldo + lnb + s * 16 + cg * 4] = t4;
            }
        }
        return;
    }

    // fp32 out epilogue (scalar 4B stores = full 64B runs per 16 lanes)
#pragma unroll
    for (int i = 0; i < 2; ++i) {
        const int gmb = m0 + wm + i * 16 + g16 * 4;
#pragma unroll
        for (int j = 0; j < 2; ++j) {
            const int gn = n0 + wn + j * 16 + l16;
            const float bv = b0[gn];
#pragma unroll
            for (int r = 0; r < 4; ++r) {
                float cv = acc[i][j][r] + bv;
                if (ACT) cv = gelu_exact(cv);
                if (RES) cv += res[(size_t)(gmb + r) * 512 + gn];
                ((float*)o0)[(size_t)(gmb + r) * N + gn] = cv;
            }
        }
    }
}

// ---------------------------------------------------------------------------
// RoPE in-place on bf16 q,k [B*T,512]. Native trig (arg <= ~1023 rad).
// ---------------------------------------------------------------------------
__global__ __launch_bounds__(256) void ropeb_k(
    unsigned short* __restrict__ q, unsigned short* __restrict__ k,
    const int* __restrict__ ts)
{
    const int idx = blockIdx.x * 256 + threadIdx.x;
    const int d  = idx & 31;
    const int nh = (idx >> 5) & (NH_ - 1);
    const int t  = (idx >> 8) & (T_ - 1);
    const int b  = idx >> 18;

    const float freq = __expf(-0.2878231366242558f * (float)d);
    const float ang = (float)ts[b * T_ + t] * freq;
    const float cc = __cosf(ang);
    const float ss = __sinf(ang);

    const size_t base = ((size_t)(b * T_ + t)) * 512 + nh * 64 + d;
    const float q1 = bf2f(q[base]), q2 = bf2f(q[base + 32]);
    q[base]      = f2bf(q1 * cc - q2 * ss);
    q[base + 32] = f2bf(q2 * cc + q1 * ss);
    const float k1 = bf2f(k[base]), k2 = bf2f(k[base + 32]);
    k[base]      = f2bf(k1 * cc - k2 * ss);
    k[base + 32] = f2bf(k2 * cc + k1 * ss);
}

// ---------------------------------------------------------------------------
// Transpose + fp32->bf16: src [R,Cc] fp32 -> dst [Cc,R] bf16. 64x64 tiles.
// ---------------------------------------------------------------------------
__global__ __launch_bounds__(256) void tconv_k(
    const float* __restrict__ src, unsigned short* __restrict__ dst,
    int R, int Cc, long slay, long dlay)
{
    __shared__ float tile[64][65];
    const int t = threadIdx.x;
    src += (size_t)blockIdx.z * slay;
    dst += (size_t)blockIdx.z * dlay;
    const int r0 = blockIdx.y * 64, c0 = blockIdx.x * 64;
    const int tr = t >> 4, tc = (t & 15) * 4;
#pragma unroll
    for (int i = 0; i < 4; ++i) {
        float4 v = *(const float4*)&src[(size_t)(r0 + tr + i * 16) * Cc + c0 + tc];
        tile[tr + i * 16][tc + 0] = v.x;
        tile[tr + i * 16][tc + 1] = v.y;
        tile[tr + i * 16][tc + 2] = v.z;
        tile[tr + i * 16][tc + 3] = v.w;
    }
    __syncthreads();
#pragma unroll
    for (int i = 0; i < 4; ++i) {
        const int n = tr + i * 16;
        ushort4 o;
        o.x = f2bf(tile[tc + 0][n]);
        o.y = f2bf(tile[tc + 1][n]);
        o.z = f2bf(tile[tc + 2][n]);
        o.w = f2bf(tile[tc + 3][n]);
        *(ushort4*)&dst[(size_t)(c0 + n) * R + r0 + tc] = o;
    }
}

// elementwise fp32 -> bf16
__global__ __launch_bounds__(256) void conv_k(
    const float* __restrict__ src, unsigned short* __restrict__ dst)
{
    const int i = (blockIdx.x * 256 + threadIdx.x) * 4;
    float4 v = *(const float4*)&src[i];
    ushort4 o = {f2bf(v.x), f2bf(v.y), f2bf(v.z), f2bf(v.w)};
    *(ushort4*)&dst[i] = o;
}

// ---------------------------------------------------------------------------
// LayerNorm over H=512, bf16 output.
// ---------------------------------------------------------------------------
__global__ __launch_bounds__(256) void ln_k(
    const float* __restrict__ x, const float* __restrict__ g,
    const float* __restrict__ b, unsigned short* __restrict__ out)
{
    const int row = blockIdx.x;
    const int tid = threadIdx.x;
    const float* xr = x + (size_t)row * H_;

    float v0 = xr[tid];
    float v1 = xr[tid + 256];

    float s = v0 + v1;
#pragma unroll
    for (int off = 32; off; off >>= 1) s += __shfl_xor(s, off);

    __shared__ float red[4];
    const int wave = tid >> 6;
    if ((tid & 63) == 0) red[wave] = s;
    __syncthreads();
    const float mean = (red[0] + red[1] + red[2] + red[3]) * (1.0f / (float)H_);

    const float d0 = v0 - mean, d1 = v1 - mean;
    float q = d0 * d0 + d1 * d1;
#pragma unroll
    for (int off = 32; off; off >>= 1) q += __shfl_xor(q, off);
    __syncthreads();
    if ((tid & 63) == 0) red[wave] = q;
    __syncthreads();
    const float var = (red[0] + red[1] + red[2] + red[3]) * (1.0f / (float)H_);
    const float rstd = rsqrtf(var + 1e-5f);

    out[(size_t)row * H_ + tid]       = f2bf(d0 * rstd * g[tid] + b[tid]);
    out[(size_t)row * H_ + tid + 256] = f2bf(d1 * rstd * g[tid + 256] + b[tid + 256]);
}

// ---------------------------------------------------------------------------
// MFMA banded attention. LDS cut 88->61 KB by aliasing Pb onto Ks (Ks is
// dead after the S-pass; one extra __syncthreads() guards the overlap) so
// 2 blocks/CU fit (was 1 -> full 2-deep serialization at 512 blocks).
// ---------------------------------------------------------------------------
#define AWIN 192
#define AKS 72
#define AVS 200

__global__ __launch_bounds__(256) void attn_k(
    const unsigned short* __restrict__ q, const unsigned short* __restrict__ k,
    const unsigned short* __restrict__ v, const int* __restrict__ smask,
    unsigned short* __restrict__ o)
{
    __shared__ unsigned short Qs[64 * AKS];
    __shared__ unsigned short Ks[AWIN * AKS];   // reused as Pb after S-pass
    __shared__ unsigned short Vt[64 * AVS];
    unsigned short* const Pb = Ks;              // 64*AVS = 12800 <= 13824

    const int blk = blockIdx.x;
    const int qt = blk & 15;
    const int h  = (blk >> 4) & 7;
    const int b  = blk >> 7;
    const int tid  = threadIdx.x;
    const int lane = tid & 63;
    const int w    = tid >> 6;
    const int l16  = lane & 15;
    const int g16  = lane >> 4;

    const int qlo = qt * 64;
    const int klo = (qlo >= CB_) ? (qlo - CB_) : 0;

    {
        const unsigned short* gq = q + ((size_t)(b * 1024 + qlo)) * 512 + h * 64;
        for (int c = tid; c < 64 * 16; c += 256) {
            const int row = c >> 4, c4 = (c & 15) * 4;
            *(ushort4*)&Qs[row * AKS + c4] = *(const ushort4*)&gq[(size_t)row * 512 + c4];
        }
        const unsigned short* gk = k + ((size_t)(b * 1024 + klo)) * 512 + h * 64;
        for (int c = tid; c < AWIN * 16; c += 256) {
            const int row = c >> 4, c4 = (c & 15) * 4;
            *(ushort4*)&Ks[row * AKS + c4] = *(const ushort4*)&gk[(size_t)row * 512 + c4];
        }
        const unsigned short* gv = v + ((size_t)(b * 1024 + klo)) * 512 + h * 64;
        for (int c = tid; c < AWIN * 16; c += 256) {
            const int row = c >> 4, c4 = (c & 15) * 4;
            ushort4 vv = *(const ushort4*)&gv[(size_t)row * 512 + c4];
            Vt[(c4 + 0) * AVS + row] = vv.x;
            Vt[(c4 + 1) * AVS + row] = vv.y;
            Vt[(c4 + 2) * AVS + row] = vv.z;
            Vt[(c4 + 3) * AVS + row] = vv.w;
        }
    }
    __syncthreads();

    // ---- S = Q @ K^T ----
    f32x4 accs[12];
    {
        const bf16x8 a0 = *(const bf16x8*)&Qs[(w * 16 + l16) * AKS + g16 * 8];
        const bf16x8 a1 = *(const bf16x8*)&Qs[(w * 16 + l16) * AKS + 32 + g16 * 8];
#pragma unroll
        for (int t = 0; t < 12; ++t) {
            const bf16x8 b0 = *(const bf16x8*)&Ks[(t * 16 + l16) * AKS + g16 * 8];
            const bf16x8 b1 = *(const bf16x8*)&Ks[(t * 16 + l16) * AKS + 32 + g16 * 8];
            f32x4 c = {};
            c = __builtin_amdgcn_mfma_f32_16x16x32_bf16(a0, b0, c, 0, 0, 0);
            c = __builtin_amdgcn_mfma_f32_16x16x32_bf16(a1, b1, c, 0, 0, 0);
            accs[t] = c;
        }
    }

    // ---- softmax in registers ----
    bool mk[12];
    int  jj[12];
#pragma unroll
    for (int t = 0; t < 12; ++t) {
        jj[t] = klo + t * 16 + l16;
        mk[t] = smask[b * 1024 + jj[t]] > 0;
    }

    float rs[4];
#pragma unroll
    for (int r = 0; r < 4; ++r) {
        const int i = qlo + 16 * w + g16 * 4 + r;
        float mx = -1e30f;
#pragma unroll
        for (int t = 0; t < 12; ++t) {
            const bool val = mk[t] && (jj[t] >= i - CB_) && (jj[t] <= i);
            mx = fmaxf(mx, val ? accs[t][r] : -1e30f);
        }
        mx = fmaxf(mx, __shfl_xor(mx, 1));
        mx = fmaxf(mx, __shfl_xor(mx, 2));
        mx = fmaxf(mx, __shfl_xor(mx, 4));
        mx = fmaxf(mx, __shfl_xor(mx, 8));
        float sum = 0.0f;
#pragma unroll
        for (int t = 0; t < 12; ++t) {
            const bool val = mk[t] && (jj[t] >= i - CB_) && (jj[t] <= i);
            const float p = val ? __expf(accs[t][r] - mx) : 0.0f;
            accs[t][r] = p;
            sum += p;
        }
        sum += __shfl_xor(sum, 1);
        sum += __shfl_xor(sum, 2);
        sum += __shfl_xor(sum, 4);
        sum += __shfl_xor(sum, 8);
        rs[r] = 1.0f / sum;
    }

    // Ks is dead from here; Pb aliases it. Guard cross-wave overlap.
    __syncthreads();

    // ---- P -> LDS ----
#pragma unroll
    for (int t = 0; t < 12; ++t)
#pragma unroll
        for (int r = 0; r < 4; ++r)
            Pb[(16 * w + g16 * 4 + r) * AVS + t * 16 + l16] = f2bf(accs[t][r]);

    // ---- O = P @ V ----
    f32x4 acco[4];
#pragma unroll
    for (int nt = 0; nt < 4; ++nt) {
        f32x4 c = {};
#pragma unroll
        for (int ks = 0; ks < 6; ++ks) {
            const bf16x8 a = *(const bf16x8*)&Pb[(16 * w + l16) * AVS + ks * 32 + g16 * 8];
            const bf16x8 bb = *(const bf16x8*)&Vt[(nt * 16 + l16) * AVS + ks * 32 + g16 * 8];
            c = __builtin_amdgcn_mfma_f32_16x16x32_bf16(a, bb, c, 0, 0, 0);
        }
        acco[nt] = c;
    }

    // ---- stage O into Pb, vector store ----
    __syncthreads();
#pragma unroll
    for (int nt = 0; nt < 4; ++nt)
#pragma unroll
        for (int r = 0; r < 4; ++r)
            Pb[(16 * w + g16 * 4 + r) * AVS + nt * 16 + l16] = f2bf(acco[nt][r] * rs[r]);

    const int row16 = lane >> 2, cg = lane & 3;
    const int grow = b * 1024 + qlo + 16 * w + row16;
#pragma unroll
    for (int s = 0; s < 4; ++s) {
        ushort4 t4 = *(const ushort4*)&Pb[(16 * w + row16) * AVS + s * 16 + cg * 4];
        *(ushort4*)&o[(size_t)grow * 512 + h * 64 + s * 16 + cg * 4] = t4;
    }
}

// ---------------------------------------------------------------------------
extern "C" void kernel_launch(void* const* d_in, const int* in_sizes, int n_in,
                              void* d_out, int out_size, void* d_ws, size_t ws_size,
                              hipStream_t stream)
{
    const float* spikes  = (const float*)d_in[0];
    const int*   smask   = (const int*)d_in[1];
    const int*   ts      = (const int*)d_in[2];
    const float* embed_w = (const float*)d_in[3];
    const float* embed_b = (const float*)d_in[4];
    const float* proj_w  = (const float*)d_in[5];
    const float* proj_b  = (const float*)d_in[6];
    const float* ln1_g   = (const float*)d_in[7];
    const float* ln1_b   = (const float*)d_in[8];
    const float* Wq      = (const float*)d_in[9];
    const float* bq      = (const float*)d_in[10];
    const float* Wk      = (const float*)d_in[11];
    const float* bk      = (const float*)d_in[12];
    const float* Wv      = (const float*)d_in[13];
    const float* bv      = (const float*)d_in[14];
    const float* Wo      = (const float*)d_in[15];
    const float* bo      = (const float*)d_in[16];
    const float* ln2_g   = (const float*)d_in[17];
    const float* ln2_b   = (const float*)d_in[18];
    const float* up_w    = (const float*)d_in[19];
    const float* up_b    = (const float*)d_in[20];
    const float* down_w  = (const float*)d_in[21];
    const float* down_b  = (const float*)d_in[22];

    const int M = B_ * T_;  // 4096

    char* p = (char*)d_ws;
    float* x = (float*)p;                       p += (size_t)M * H_ * 4;
    unsigned short* qb  = (unsigned short*)p;   p += (size_t)M * H_ * 2;
    unsigned short* kb  = (unsigned short*)p;   p += (size_t)M * H_ * 2;
    unsigned short* vb  = (unsigned short*)p;   p += (size_t)M * H_ * 2;
    unsigned short* hbf = (unsigned short*)p;   p += (size_t)M * H_ * 2;
    unsigned short* obf = (unsigned short*)p;   p += (size_t)M * H_ * 2;
    unsigned short* ibf = (unsigned short*)p;   p += (size_t)M * INTER_ * 2;
    unsigned short* tbf = (unsigned short*)p;   p += (size_t)M * D_ * 2;
    unsigned short* spbf  = (unsigned short*)p; p += (size_t)M * C_ * 2;
    unsigned short* embT  = (unsigned short*)p; p += (size_t)D_ * C_ * 2;
    unsigned short* projT = (unsigned short*)p; p += (size_t)H_ * D_ * 2;
    unsigned short* qkvT  = (unsigned short*)p; p += (size_t)L_ * 3 * H_ * H_ * 2;
    unsigned short* woT   = (unsigned short*)p; p += (size_t)L_ * H_ * H_ * 2;
    unsigned short* upT   = (unsigned short*)p; p += (size_t)L_ * INTER_ * H_ * 2;
    unsigned short* downT = (unsigned short*)p; p += (size_t)L_ * H_ * INTER_ * 2;

    // ---- prologue ----
    conv_k<<<(M * C_) / 1024, 256, 0, stream>>>(spikes, spbf);
    tconv_k<<<dim3(D_ / 64, C_ / 64, 1), 256, 0, stream>>>(embed_w, embT, C_, D_, 0, 0);
    tconv_k<<<dim3(H_ / 64, D_ / 64, 1), 256, 0, stream>>>(proj_w, projT, D_, H_, 0, 0);
    tconv_k<<<dim3(H_ / 64, H_ / 64, L_), 256, 0, stream>>>(
        Wq, qkvT,               H_, H_, (long)H_ * H_, (long)3 * H_ * H_);
    tconv_k<<<dim3(H_ / 64, H_ / 64, L_), 256, 0, stream>>>(
        Wk, qkvT + H_ * H_,     H_, H_, (long)H_ * H_, (long)3 * H_ * H_);
    tconv_k<<<dim3(H_ / 64, H_ / 64, L_), 256, 0, stream>>>(
        Wv, qkvT + 2 * H_ * H_, H_, H_, (long)H_ * H_, (long)3 * H_ * H_);
    tconv_k<<<dim3(H_ / 64, H_ / 64, L_), 256, 0, stream>>>(
        Wo, woT, H_, H_, (long)H_ * H_, (long)H_ * H_);
    tconv_k<<<dim3(INTER_ / 64, H_ / 64, L_), 256, 0, stream>>>(
        up_w, upT, H_, INTER_, (long)H_ * INTER_, (long)INTER_ * H_);
    tconv_k<<<dim3(H_ / 64, INTER_ / 64, L_), 256, 0, stream>>>(
        down_w, downT, INTER_, H_, (long)INTER_ * H_, (long)H_ * INTER_);

    // ---- embedding ----
    mm64_k<1, 0, 1, 0><<<dim3(D_ / 64, M / 64), 256, 0, stream>>>(
        spbf, embT, embed_b, nullptr, nullptr, nullptr,
        tbf, nullptr, nullptr, M, D_, C_);
    mm64_k<0, 0, 0, 0><<<dim3(H_ / 64, M / 64), 256, 0, stream>>>(
        tbf, projT, proj_b, nullptr, nullptr, nullptr,
        x, nullptr, nullptr, M, H_, D_);

    for (int l = 0; l < L_; ++l) {
        const unsigned short* qkvT_l = qkvT + (size_t)l * 3 * H_ * H_;
        const unsigned short* woT_l  = woT  + (size_t)l * H_ * H_;
        const unsigned short* upT_l  = upT  + (size_t)l * INTER_ * H_;
        const unsigned short* dnT_l  = downT + (size_t)l * H_ * INTER_;

        ln_k<<<M, 256, 0, stream>>>(x, ln1_g + l * H_, ln1_b + l * H_, hbf);

        // fused QKV + bias (+0.125 q scale) -> qb, kb, vb (bf16 [M,512])
        mm64_k<0, 0, 1, 1><<<dim3((3 * H_) / 64, M / 64), 256, 0, stream>>>(
            hbf, qkvT_l, bq + l * H_, bk + l * H_, bv + l * H_, nullptr,
            qb, kb, vb, M, 3 * H_, H_);

        ropeb_k<<<(B_ * T_ * NH_ * 32) / 256, 256, 0, stream>>>(qb, kb, ts);

        attn_k<<<B_ * NH_ * (T_ / 64), 256, 0, stream>>>(qb, kb, vb, smask, obf);

        // x = x + obuf @ Wo + bo
        mm64_k<0, 1, 0, 0><<<dim3(H_ / 64, M / 64), 256, 0, stream>>>(
            obf, woT_l, bo + l * H_, nullptr, nullptr, x,
            x, nullptr, nullptr, M, H_, H_);

        ln_k<<<M, 256, 0, stream>>>(x, ln2_g + l * H_, ln2_b + l * H_, hbf);

        // inter = gelu(h @ up_w + b)
        mm64_k<1, 0, 1, 0><<<dim3(INTER_ / 64, M / 64), 256, 0, stream>>>(
            hbf, upT_l, up_b + l * INTER_, nullptr, nullptr, nullptr,
            ibf, nullptr, nullptr, M, INTER_, H_);

        // x = x + inter @ down_w + b
        float* dst = (l == L_ - 1) ? (float*)d_out : x;
        mm64_k<0, 1, 0, 0><<<dim3(H_ / 64, M / 64), 256, 0, stream>>>(
            ibf, dnT_l, down_b + l * H_, nullptr, nullptr, x,
            dst, nullptr, nullptr, M, H_, INTER_);
    }
}

// Round 10
// 542.055 us; speedup vs baseline: 2.4347x; 1.1600x over previous
//
#include <hip/hip_runtime.h>
#include <math.h>

// Problem dims (fixed)
#define B_ 4
#define T_ 1024
#define C_ 256
#define D_ 256
#define H_ 512
#define NH_ 8
#define HD_ 64
#define INTER_ 2048
#define L_ 4
#define CB_ 128   // context_backward; context_forward = 0

typedef short bf16x8 __attribute__((ext_vector_type(8)));
typedef float f32x4 __attribute__((ext_vector_type(4)));

__device__ __forceinline__ float gelu_exact(float x) {
    return 0.5f * x * (1.0f + erff(x * 0.70710678118654752f));
}

// fp32 -> bf16 round-to-nearest-even
__device__ __forceinline__ unsigned short f2bf(float f) {
    unsigned u = __float_as_uint(f);
    u += 0x7fffu + ((u >> 16) & 1u);
    return (unsigned short)(u >> 16);
}
__device__ __forceinline__ float bf2f(unsigned short h) {
    return __uint_as_float((unsigned)h << 16);
}

// ---------------------------------------------------------------------------
// bf16 MFMA GEMM, 64x64 tile, BK=64, XOR-swizzled LDS staging.
// Swizzle: chunk (row, g) of the 16B-granular tile stores global k-group
// g ^ (row&7). global_load_lds destinations stay chunk-contiguous (the
// wave-uniform-base constraint), while MFMA frag reads spread over all 32
// banks (2-way aliasing = free, vs 8-way with the naive 64B-stride layout
// that R9's 2.2M SQ_LDS_BANK_CONFLICT came from). BK=64 halves barrier
// count vs R9 (8 MFMAs + 4 load-issues per barrier pair).
// SPLIT=1: QKV mode, N=1536: routes output/bias by 32-col strip, scales q
// by 0.125. No trig here (R4/R5 lesson). bf16 outputs via per-wave in-LDS
// transpose -> ushort4 stores (R4 lesson: avoid scalar/scatter bf16 stores).
// ---------------------------------------------------------------------------
template<int ACT, int RES, int OBF, int SPLIT>
__global__ __launch_bounds__(256) void mm64_k(
    const unsigned short* __restrict__ A, const unsigned short* __restrict__ BT,
    const float* __restrict__ b0, const float* __restrict__ b1,
    const float* __restrict__ b2,
    const float* res,
    void* o0, void* o1, void* o2,
    const int M, const int N, const int K)
{
    __shared__ unsigned short As[64 * 64];
    __shared__ unsigned short Bs[64 * 64];

    const int tid  = threadIdx.x;
    const int lane = tid & 63;
    const int w    = tid >> 6;
    const int m0   = blockIdx.y * 64;
    const int n0   = blockIdx.x * 64;
    const int wm   = (w >> 1) * 32;
    const int wn   = (w & 1) * 32;
    const int l16  = lane & 15;
    const int g16  = lane >> 4;

    f32x4 acc[2][2] = {};

    const unsigned short* Abase = A  + (size_t)m0 * K;
    const unsigned short* Bbase = BT + (size_t)n0 * K;

    // staging chunks: c0 = w*64+lane (rows 8w..8w+7), c1 = c0+256 (rows 32..63)
    const int c0 = (w << 6) + lane;
    const int c1 = c0 + 256;
    const int r0c = c0 >> 3, g0c = c0 & 7, gk0 = g0c ^ (r0c & 7);
    const int r1c = c1 >> 3, g1c = c1 & 7, gk1 = g1c ^ (r1c & 7);

    for (int k0 = 0; k0 < K; k0 += 64) {
        __syncthreads();
        __builtin_amdgcn_global_load_lds(
            (const __attribute__((address_space(1))) unsigned*)(Abase + (size_t)r0c * K + k0 + gk0 * 8),
            (__attribute__((address_space(3))) unsigned*)(As + (size_t)(w << 6) * 8), 16, 0, 0);
        __builtin_amdgcn_global_load_lds(
            (const __attribute__((address_space(1))) unsigned*)(Abase + (size_t)r1c * K + k0 + gk1 * 8),
            (__attribute__((address_space(3))) unsigned*)(As + (size_t)(256 + (w << 6)) * 8), 16, 0, 0);
        __builtin_amdgcn_global_load_lds(
            (const __attribute__((address_space(1))) unsigned*)(Bbase + (size_t)r0c * K + k0 + gk0 * 8),
            (__attribute__((address_space(3))) unsigned*)(Bs + (size_t)(w << 6) * 8), 16, 0, 0);
        __builtin_amdgcn_global_load_lds(
            (const __attribute__((address_space(1))) unsigned*)(Bbase + (size_t)r1c * K + k0 + gk1 * 8),
            (__attribute__((address_space(3))) unsigned*)(Bs + (size_t)(256 + (w << 6)) * 8), 16, 0, 0);
        __syncthreads();

#pragma unroll
        for (int kk = 0; kk < 2; ++kk) {
            const int kf = kk * 4 + g16;            // global k-group 0..7
            const int sw = (kf ^ (l16 & 7)) * 8;    // swizzled ushort offset
            bf16x8 a[2], b[2];
#pragma unroll
            for (int t = 0; t < 2; ++t)
                a[t] = *(const bf16x8*)&As[(wm + t * 16 + l16) * 64 + sw];
#pragma unroll
            for (int t = 0; t < 2; ++t)
                b[t] = *(const bf16x8*)&Bs[(wn + t * 16 + l16) * 64 + sw];
#pragma unroll
            for (int i = 0; i < 2; ++i)
#pragma unroll
                for (int j = 0; j < 2; ++j)
                    acc[i][j] = __builtin_amdgcn_mfma_f32_16x16x32_bf16(a[i], b[j], acc[i][j], 0, 0, 0);
        }
    }

    if (OBF || SPLIT) {
        __syncthreads();
        unsigned short* Eb = ((w < 2) ? As : Bs) + (w & 1) * 1024;
        const int row16 = lane >> 2;
        const int cg    = lane & 3;

        const int gnb   = n0 + wn;
        const int which = SPLIT ? (gnb >> 9) : 0;
        const int lnb   = SPLIT ? (gnb & 511) : gnb;
        const int ldo   = SPLIT ? 512 : N;
        unsigned short* oo = SPLIT
            ? ((which == 0) ? (unsigned short*)o0 : (which == 1) ? (unsigned short*)o1 : (unsigned short*)o2)
            : (unsigned short*)o0;
        const float* bb = SPLIT ? ((which == 0) ? b0 : (which == 1) ? b1 : b2) : b0;
        const float scale = (SPLIT && which == 0) ? 0.125f : 1.0f;

#pragma unroll
        for (int i = 0; i < 2; ++i) {
#pragma unroll
            for (int j = 0; j < 2; ++j) {
                const float bv = bb[lnb + j * 16 + l16];
#pragma unroll
                for (int r = 0; r < 4; ++r) {
                    float cv = acc[i][j][r] + bv;
                    if (ACT) cv = gelu_exact(cv);
                    if (SPLIT) cv *= scale;
                    Eb[(g16 * 4 + r) * 40 + j * 16 + l16] = f2bf(cv);
                }
            }
            const int grow0 = m0 + wm + i * 16 + row16;
#pragma unroll
            for (int s = 0; s < 2; ++s) {
                ushort4 t4 = *(const ushort4*)&Eb[row16 * 40 + s * 16 + cg * 4];
                *(ushort4*)&oo[(size_t)grow0 * ldo + lnb + s * 16 + cg * 4] = t4;
            }
        }
        return;
    }

    // fp32 out epilogue (scalar 4B stores = full 64B runs per 16 lanes)
#pragma unroll
    for (int i = 0; i < 2; ++i) {
        const int gmb = m0 + wm + i * 16 + g16 * 4;
#pragma unroll
        for (int j = 0; j < 2; ++j) {
            const int gn = n0 + wn + j * 16 + l16;
            const float bv = b0[gn];
#pragma unroll
            for (int r = 0; r < 4; ++r) {
                float cv = acc[i][j][r] + bv;
                if (ACT) cv = gelu_exact(cv);
                if (RES) cv += res[(size_t)(gmb + r) * 512 + gn];
                ((float*)o0)[(size_t)(gmb + r) * N + gn] = cv;
            }
        }
    }
}

// ---------------------------------------------------------------------------
// Fused prologue: ONE dispatch replaces 8 tconv + 1 conv (R9 paid ~10 serial
// launches for ~12 us of traffic). Block index decodes which weight / layer /
// 64x64 tile; last 256 blocks convert spikes elementwise.
// ---------------------------------------------------------------------------
__global__ __launch_bounds__(256) void prep_k(
    const float* __restrict__ spikes,
    const float* __restrict__ embed_w, const float* __restrict__ proj_w,
    const float* __restrict__ Wq, const float* __restrict__ Wk,
    const float* __restrict__ Wv, const float* __restrict__ Wo,
    const float* __restrict__ up_w, const float* __restrict__ down_w,
    unsigned short* __restrict__ spbf,
    unsigned short* __restrict__ embT, unsigned short* __restrict__ projT,
    unsigned short* __restrict__ qkvT, unsigned short* __restrict__ woT,
    unsigned short* __restrict__ upT, unsigned short* __restrict__ downT)
{
    const int idx = blockIdx.x;
    const int tid = threadIdx.x;

    if (idx >= 3120) {  // spikes fp32->bf16: 256 blocks x 4096 elems
        const int base = (idx - 3120) * 4096 + tid * 16;
#pragma unroll
        for (int s = 0; s < 4; ++s) {
            float4 v = *(const float4*)&spikes[base + s * 4];
            ushort4 o = {f2bf(v.x), f2bf(v.y), f2bf(v.z), f2bf(v.w)};
            *(ushort4*)&spbf[base + s * 4] = o;
        }
        return;
    }

    const float* src; unsigned short* dst; int R, Cc, t;
    if (idx < 16)      { src = embed_w; dst = embT;  R = C_; Cc = D_; t = idx; }
    else if (idx < 48) { src = proj_w;  dst = projT; R = D_; Cc = H_; t = idx - 16; }
    else if (idx < 816) {
        const int j = idx - 48;        // 0..767: Wq | Wk | Wv, 4 layers x 64 tiles
        const int wsel = j >> 8;
        const int l = (j & 255) >> 6;
        t = j & 63;
        src = ((wsel == 0) ? Wq : (wsel == 1) ? Wk : Wv) + (size_t)l * H_ * H_;
        dst = qkvT + (size_t)l * 3 * H_ * H_ + (size_t)wsel * H_ * H_;
        R = H_; Cc = H_;
    } else if (idx < 1072) {
        const int j = idx - 816; const int l = j >> 6; t = j & 63;
        src = Wo + (size_t)l * H_ * H_; dst = woT + (size_t)l * H_ * H_;
        R = H_; Cc = H_;
    } else if (idx < 2096) {
        const int j = idx - 1072; const int l = j >> 8; t = j & 255;
        src = up_w + (size_t)l * H_ * INTER_; dst = upT + (size_t)l * INTER_ * H_;
        R = H_; Cc = INTER_;
    } else {
        const int j = idx - 2096; const int l = j >> 8; t = j & 255;
        src = down_w + (size_t)l * INTER_ * H_; dst = downT + (size_t)l * H_ * INTER_;
        R = INTER_; Cc = H_;
    }
    const int ntx = Cc >> 6;
    const int c0 = (t % ntx) * 64, r0 = (t / ntx) * 64;

    __shared__ float tile[64][65];
    const int tr = tid >> 4, tc = (tid & 15) * 4;
#pragma unroll
    for (int i = 0; i < 4; ++i) {
        float4 v = *(const float4*)&src[(size_t)(r0 + tr + i * 16) * Cc + c0 + tc];
        tile[tr + i * 16][tc + 0] = v.x;
        tile[tr + i * 16][tc + 1] = v.y;
        tile[tr + i * 16][tc + 2] = v.z;
        tile[tr + i * 16][tc + 3] = v.w;
    }
    __syncthreads();
#pragma unroll
    for (int i = 0; i < 4; ++i) {
        const int n = tr + i * 16;
        ushort4 o;
        o.x = f2bf(tile[tc + 0][n]);
        o.y = f2bf(tile[tc + 1][n]);
        o.z = f2bf(tile[tc + 2][n]);
        o.w = f2bf(tile[tc + 3][n]);
        *(ushort4*)&dst[(size_t)(c0 + n) * R + r0 + tc] = o;
    }
}

// ---------------------------------------------------------------------------
// LayerNorm over H=512, bf16 output.
// ---------------------------------------------------------------------------
__global__ __launch_bounds__(256) void ln_k(
    const float* __restrict__ x, const float* __restrict__ g,
    const float* __restrict__ b, unsigned short* __restrict__ out)
{
    const int row = blockIdx.x;
    const int tid = threadIdx.x;
    const float* xr = x + (size_t)row * H_;

    float v0 = xr[tid];
    float v1 = xr[tid + 256];

    float s = v0 + v1;
#pragma unroll
    for (int off = 32; off; off >>= 1) s += __shfl_xor(s, off);

    __shared__ float red[4];
    const int wave = tid >> 6;
    if ((tid & 63) == 0) red[wave] = s;
    __syncthreads();
    const float mean = (red[0] + red[1] + red[2] + red[3]) * (1.0f / (float)H_);

    const float d0 = v0 - mean, d1 = v1 - mean;
    float q = d0 * d0 + d1 * d1;
#pragma unroll
    for (int off = 32; off; off >>= 1) q += __shfl_xor(q, off);
    __syncthreads();
    if ((tid & 63) == 0) red[wave] = q;
    __syncthreads();
    const float var = (red[0] + red[1] + red[2] + red[3]) * (1.0f / (float)H_);
    const float rstd = rsqrtf(var + 1e-5f);

    out[(size_t)row * H_ + tid]       = f2bf(d0 * rstd * g[tid] + b[tid]);
    out[(size_t)row * H_ + tid + 256] = f2bf(d1 * rstd * g[tid + 256] + b[tid + 256]);
}

// ---------------------------------------------------------------------------
// MFMA banded attention with RoPE fused into Q/K staging (removes the
// standalone rope pass + its q/k round-trip; native __cosf/__sinf, arg
// <= ~1023 rad, err ~1e-4 << bf16 eps). LDS: Pb aliases Ks (dead after
// S-pass) -> 61 KB, 2 blocks/CU.
// ---------------------------------------------------------------------------
#define AWIN 192
#define AKS 72
#define AVS 200

__global__ __launch_bounds__(256) void attn_k(
    const unsigned short* __restrict__ q, const unsigned short* __restrict__ k,
    const unsigned short* __restrict__ v, const int* __restrict__ smask,
    const int* __restrict__ ts, unsigned short* __restrict__ o)
{
    __shared__ unsigned short Qs[64 * AKS];
    __shared__ unsigned short Ks[AWIN * AKS];   // reused as Pb after S-pass
    __shared__ unsigned short Vt[64 * AVS];
    unsigned short* const Pb = Ks;              // 64*AVS = 12800 <= 13824

    const int blk = blockIdx.x;
    const int qt = blk & 15;
    const int h  = (blk >> 4) & 7;
    const int b  = blk >> 7;
    const int tid  = threadIdx.x;
    const int lane = tid & 63;
    const int w    = tid >> 6;
    const int l16  = lane & 15;
    const int g16  = lane >> 4;

    const int qlo = qt * 64;
    const int klo = (qlo >= CB_) ? (qlo - CB_) : 0;
    const int tb  = b * 1024;

    // ---- stage Q with RoPE (q pre-scaled 0.125 in QKV epilogue) ----
    {
        const unsigned short* gq = q + ((size_t)(tb + qlo)) * 512 + h * 64;
        for (int c = tid; c < 64 * 8; c += 256) {
            const int row = c >> 3, c4 = (c & 7) * 4;   // d = c4..c4+3 in [0,32)
            ushort4 lo = *(const ushort4*)&gq[(size_t)row * 512 + c4];
            ushort4 hi = *(const ushort4*)&gq[(size_t)row * 512 + c4 + 32];
            const float tstamp = (float)ts[tb + qlo + row];
            ushort4 olo, ohi;
#pragma unroll
            for (int j2 = 0; j2 < 4; ++j2) {
                const float freq = __expf(-0.2878231366242558f * (float)(c4 + j2));
                const float ang = tstamp * freq;
                const float cc = __cosf(ang), ss = __sinf(ang);
                const float v1 = bf2f(((const unsigned short*)&lo)[j2]);
                const float v2 = bf2f(((const unsigned short*)&hi)[j2]);
                ((unsigned short*)&olo)[j2] = f2bf(v1 * cc - v2 * ss);
                ((unsigned short*)&ohi)[j2] = f2bf(v2 * cc + v1 * ss);
            }
            *(ushort4*)&Qs[row * AKS + c4]      = olo;
            *(ushort4*)&Qs[row * AKS + c4 + 32] = ohi;
        }
    }
    // ---- stage K with RoPE ----
    {
        const unsigned short* gk = k + ((size_t)(tb + klo)) * 512 + h * 64;
        for (int c = tid; c < AWIN * 8; c += 256) {
            const int row = c >> 3, c4 = (c & 7) * 4;
            ushort4 lo = *(const ushort4*)&gk[(size_t)row * 512 + c4];
            ushort4 hi = *(const ushort4*)&gk[(size_t)row * 512 + c4 + 32];
            const float tstamp = (float)ts[tb + klo + row];
            ushort4 olo, ohi;
#pragma unroll
            for (int j2 = 0; j2 < 4; ++j2) {
                const float freq = __expf(-0.2878231366242558f * (float)(c4 + j2));
                const float ang = tstamp * freq;
                const float cc = __cosf(ang), ss = __sinf(ang);
                const float v1 = bf2f(((const unsigned short*)&lo)[j2]);
                const float v2 = bf2f(((const unsigned short*)&hi)[j2]);
                ((unsigned short*)&olo)[j2] = f2bf(v1 * cc - v2 * ss);
                ((unsigned short*)&ohi)[j2] = f2bf(v2 * cc + v1 * ss);
            }
            *(ushort4*)&Ks[row * AKS + c4]      = olo;
            *(ushort4*)&Ks[row * AKS + c4 + 32] = ohi;
        }
    }
    // ---- stage V (transposed into LDS) ----
    {
        const unsigned short* gv = v + ((size_t)(tb + klo)) * 512 + h * 64;
        for (int c = tid; c < AWIN * 16; c += 256) {
            const int row = c >> 4, c4 = (c & 15) * 4;
            ushort4 vv = *(const ushort4*)&gv[(size_t)row * 512 + c4];
            Vt[(c4 + 0) * AVS + row] = vv.x;
            Vt[(c4 + 1) * AVS + row] = vv.y;
            Vt[(c4 + 2) * AVS + row] = vv.z;
            Vt[(c4 + 3) * AVS + row] = vv.w;
        }
    }
    __syncthreads();

    // ---- S = Q @ K^T ----
    f32x4 accs[12];
    {
        const bf16x8 a0 = *(const bf16x8*)&Qs[(w * 16 + l16) * AKS + g16 * 8];
        const bf16x8 a1 = *(const bf16x8*)&Qs[(w * 16 + l16) * AKS + 32 + g16 * 8];
#pragma unroll
        for (int t = 0; t < 12; ++t) {
            const bf16x8 b0 = *(const bf16x8*)&Ks[(t * 16 + l16) * AKS + g16 * 8];
            const bf16x8 b1 = *(const bf16x8*)&Ks[(t * 16 + l16) * AKS + 32 + g16 * 8];
            f32x4 c = {};
            c = __builtin_amdgcn_mfma_f32_16x16x32_bf16(a0, b0, c, 0, 0, 0);
            c = __builtin_amdgcn_mfma_f32_16x16x32_bf16(a1, b1, c, 0, 0, 0);
            accs[t] = c;
        }
    }

    // ---- softmax in registers ----
    bool mk[12];
    int  jj[12];
#pragma unroll
    for (int t = 0; t < 12; ++t) {
        jj[t] = klo + t * 16 + l16;
        mk[t] = smask[tb + jj[t]] > 0;
    }

    float rs[4];
#pragma unroll
    for (int r = 0; r < 4; ++r) {
        const int i = qlo + 16 * w + g16 * 4 + r;
        float mx = -1e30f;
#pragma unroll
        for (int t = 0; t < 12; ++t) {
            const bool val = mk[t] && (jj[t] >= i - CB_) && (jj[t] <= i);
            mx = fmaxf(mx, val ? accs[t][r] : -1e30f);
        }
        mx = fmaxf(mx, __shfl_xor(mx, 1));
        mx = fmaxf(mx, __shfl_xor(mx, 2));
        mx = fmaxf(mx, __shfl_xor(mx, 4));
        mx = fmaxf(mx, __shfl_xor(mx, 8));
        float sum = 0.0f;
#pragma unroll
        for (int t = 0; t < 12; ++t) {
            const bool val = mk[t] && (jj[t] >= i - CB_) && (jj[t] <= i);
            const float p = val ? __expf(accs[t][r] - mx) : 0.0f;
            accs[t][r] = p;
            sum += p;
        }
        sum += __shfl_xor(sum, 1);
        sum += __shfl_xor(sum, 2);
        sum += __shfl_xor(sum, 4);
        sum += __shfl_xor(sum, 8);
        rs[r] = 1.0f / sum;
    }

    // Ks dead from here; Pb aliases it.
    __syncthreads();

    // ---- P -> LDS ----
#pragma unroll
    for (int t = 0; t < 12; ++t)
#pragma unroll
        for (int r = 0; r < 4; ++r)
            Pb[(16 * w + g16 * 4 + r) * AVS + t * 16 + l16] = f2bf(accs[t][r]);

    // ---- O = P @ V ----
    f32x4 acco[4];
#pragma unroll
    for (int nt = 0; nt < 4; ++nt) {
        f32x4 c = {};
#pragma unroll
        for (int ks = 0; ks < 6; ++ks) {
            const bf16x8 a = *(const bf16x8*)&Pb[(16 * w + l16) * AVS + ks * 32 + g16 * 8];
            const bf16x8 bb = *(const bf16x8*)&Vt[(nt * 16 + l16) * AVS + ks * 32 + g16 * 8];
            c = __builtin_amdgcn_mfma_f32_16x16x32_bf16(a, bb, c, 0, 0, 0);
        }
        acco[nt] = c;
    }

    // ---- stage O into Pb, vector store ----
    __syncthreads();
#pragma unroll
    for (int nt = 0; nt < 4; ++nt)
#pragma unroll
        for (int r = 0; r < 4; ++r)
            Pb[(16 * w + g16 * 4 + r) * AVS + nt * 16 + l16] = f2bf(acco[nt][r] * rs[r]);

    const int row16 = lane >> 2, cg = lane & 3;
    const int grow = tb + qlo + 16 * w + row16;
#pragma unroll
    for (int s = 0; s < 4; ++s) {
        ushort4 t4 = *(const ushort4*)&Pb[(16 * w + row16) * AVS + s * 16 + cg * 4];
        *(ushort4*)&o[(size_t)grow * 512 + h * 64 + s * 16 + cg * 4] = t4;
    }
}

// ---------------------------------------------------------------------------
extern "C" void kernel_launch(void* const* d_in, const int* in_sizes, int n_in,
                              void* d_out, int out_size, void* d_ws, size_t ws_size,
                              hipStream_t stream)
{
    const float* spikes  = (const float*)d_in[0];
    const int*   smask   = (const int*)d_in[1];
    const int*   ts      = (const int*)d_in[2];
    const float* embed_w = (const float*)d_in[3];
    const float* embed_b = (const float*)d_in[4];
    const float* proj_w  = (const float*)d_in[5];
    const float* proj_b  = (const float*)d_in[6];
    const float* ln1_g   = (const float*)d_in[7];
    const float* ln1_b   = (const float*)d_in[8];
    const float* Wq      = (const float*)d_in[9];
    const float* bq      = (const float*)d_in[10];
    const float* Wk      = (const float*)d_in[11];
    const float* bk      = (const float*)d_in[12];
    const float* Wv      = (const float*)d_in[13];
    const float* bv      = (const float*)d_in[14];
    const float* Wo      = (const float*)d_in[15];
    const float* bo      = (const float*)d_in[16];
    const float* ln2_g   = (const float*)d_in[17];
    const float* ln2_b   = (const float*)d_in[18];
    const float* up_w    = (const float*)d_in[19];
    const float* up_b    = (const float*)d_in[20];
    const float* down_w  = (const float*)d_in[21];
    const float* down_b  = (const float*)d_in[22];

    const int M = B_ * T_;  // 4096

    char* p = (char*)d_ws;
    float* x = (float*)p;                       p += (size_t)M * H_ * 4;
    unsigned short* qb  = (unsigned short*)p;   p += (size_t)M * H_ * 2;
    unsigned short* kb  = (unsigned short*)p;   p += (size_t)M * H_ * 2;
    unsigned short* vb  = (unsigned short*)p;   p += (size_t)M * H_ * 2;
    unsigned short* hbf = (unsigned short*)p;   p += (size_t)M * H_ * 2;
    unsigned short* obf = (unsigned short*)p;   p += (size_t)M * H_ * 2;
    unsigned short* ibf = (unsigned short*)p;   p += (size_t)M * INTER_ * 2;
    unsigned short* tbf = (unsigned short*)p;   p += (size_t)M * D_ * 2;
    unsigned short* spbf  = (unsigned short*)p; p += (size_t)M * C_ * 2;
    unsigned short* embT  = (unsigned short*)p; p += (size_t)D_ * C_ * 2;
    unsigned short* projT = (unsigned short*)p; p += (size_t)H_ * D_ * 2;
    unsigned short* qkvT  = (unsigned short*)p; p += (size_t)L_ * 3 * H_ * H_ * 2;
    unsigned short* woT   = (unsigned short*)p; p += (size_t)L_ * H_ * H_ * 2;
    unsigned short* upT   = (unsigned short*)p; p += (size_t)L_ * INTER_ * H_ * 2;
    unsigned short* downT = (unsigned short*)p; p += (size_t)L_ * H_ * INTER_ * 2;

    // ---- fused prologue: all weight transposes + spikes convert, 1 dispatch
    prep_k<<<3376, 256, 0, stream>>>(
        spikes, embed_w, proj_w, Wq, Wk, Wv, Wo, up_w, down_w,
        spbf, embT, projT, qkvT, woT, upT, downT);

    // ---- embedding ----
    mm64_k<1, 0, 1, 0><<<dim3(D_ / 64, M / 64), 256, 0, stream>>>(
        spbf, embT, embed_b, nullptr, nullptr, nullptr,
        tbf, nullptr, nullptr, M, D_, C_);
    mm64_k<0, 0, 0, 0><<<dim3(H_ / 64, M / 64), 256, 0, stream>>>(
        tbf, projT, proj_b, nullptr, nullptr, nullptr,
        x, nullptr, nullptr, M, H_, D_);

    for (int l = 0; l < L_; ++l) {
        const unsigned short* qkvT_l = qkvT + (size_t)l * 3 * H_ * H_;
        const unsigned short* woT_l  = woT  + (size_t)l * H_ * H_;
        const unsigned short* upT_l  = upT  + (size_t)l * INTER_ * H_;
        const unsigned short* dnT_l  = downT + (size_t)l * H_ * INTER_;

        ln_k<<<M, 256, 0, stream>>>(x, ln1_g + l * H_, ln1_b + l * H_, hbf);

        // fused QKV + bias (+0.125 q scale) -> qb, kb, vb (bf16 [M,512])
        mm64_k<0, 0, 1, 1><<<dim3((3 * H_) / 64, M / 64), 256, 0, stream>>>(
            hbf, qkvT_l, bq + l * H_, bk + l * H_, bv + l * H_, nullptr,
            qb, kb, vb, M, 3 * H_, H_);

        // attention (RoPE fused into staging)
        attn_k<<<B_ * NH_ * (T_ / 64), 256, 0, stream>>>(qb, kb, vb, smask, ts, obf);

        // x = x + obuf @ Wo + bo
        mm64_k<0, 1, 0, 0><<<dim3(H_ / 64, M / 64), 256, 0, stream>>>(
            obf, woT_l, bo + l * H_, nullptr, nullptr, x,
            x, nullptr, nullptr, M, H_, H_);

        ln_k<<<M, 256, 0, stream>>>(x, ln2_g + l * H_, ln2_b + l * H_, hbf);

        // inter = gelu(h @ up_w + b)
        mm64_k<1, 0, 1, 0><<<dim3(INTER_ / 64, M / 64), 256, 0, stream>>>(
            hbf, upT_l, up_b + l * INTER_, nullptr, nullptr, nullptr,
            ibf, nullptr, nullptr, M, INTER_, H_);

        // x = x + inter @ down_w + b
        float* dst = (l == L_ - 1) ? (float*)d_out : x;
        mm64_k<0, 1, 0, 0><<<dim3(H_ / 64, M / 64), 256, 0, stream>>>(
            ibf, dnT_l, down_b + l * H_, nullptr, nullptr, x,
            dst, nullptr, nullptr, M, H_, INTER_);
    }
}